// Round 1
// baseline (290.124 us; speedup 1.0000x reference)
//
#include <hip/hip_runtime.h>
#include <stdint.h>
#include <stddef.h>

// EuclideanAttention MI355X implementation, round 1.
// B=2 S=2048 E=1024 H=16 D=64. 68.8 GFLOP total -> all-MFMA bf16 pipeline.
//   attn = softmax(min(2qk - k^2, q^2) / T)  (q^2 row-shift cancels in softmax)
// Stages: convX -> transposeW -> fused QKV GEMM -> sumsq -> flash attn -> out GEMM.
// ws usage ~51 MB.

#define LOG2E 1.44269504088896f

typedef __attribute__((ext_vector_type(8))) short bf16x8;
typedef __attribute__((ext_vector_type(4))) float f32x4;
typedef __attribute__((ext_vector_type(4))) unsigned short u16x4;

__device__ __forceinline__ unsigned short f2b(float f) {
  union { float f; unsigned int u; } x; x.f = f;
  unsigned int u = x.u;
  u += 0x7fffu + ((u >> 16) & 1u);   // RNE
  return (unsigned short)(u >> 16);
}
__device__ __forceinline__ float b2f(unsigned short s) {
  union { unsigned int u; float f; } x; x.u = ((unsigned int)s) << 16;
  return x.f;
}

// async global->LDS, 16B per lane. LDS dest = uniform base + lane*16 (m104/m108).
#define GLD_LDS(g, l) __builtin_amdgcn_global_load_lds( \
    (const __attribute__((address_space(1))) void*)(g), \
    (__attribute__((address_space(3))) void*)(l), 16, 0, 0)

// ---------------------------------------------------------------- convX
__global__ void convx_kernel(const float* __restrict__ X, unsigned short* __restrict__ Xb) {
  int i = (blockIdx.x * 256 + threadIdx.x) * 4;
  f32x4 v = *(const f32x4*)&X[i];
  u16x4 o;
  #pragma unroll
  for (int j = 0; j < 4; ++j) o[j] = f2b(v[j]);
  *(u16x4*)&Xb[i] = o;
}

// ------------------------------------------------------------- transposeW
// W [k=1024][n=1024] fp32 -> WT [n][k] bf16.  64x64 LDS tiles.
__global__ void transw_kernel(const float* __restrict__ wq, const float* __restrict__ wk,
                              const float* __restrict__ wv, const float* __restrict__ wo,
                              unsigned short* __restrict__ WTqkv, unsigned short* __restrict__ WTo) {
  __shared__ float tile[64][65];
  int z = blockIdx.z;
  const float* src = (z == 0) ? wq : (z == 1) ? wk : (z == 2) ? wv : wo;
  unsigned short* dst = (z < 3) ? (WTqkv + (size_t)z * 1024 * 1024) : WTo;
  int k0 = blockIdx.y * 64, n0 = blockIdx.x * 64;
  int rr = threadIdx.x >> 6, cc = threadIdx.x & 63;
  #pragma unroll
  for (int p = 0; p < 16; ++p) {
    int row = p * 4 + rr;
    tile[row][cc] = src[(size_t)(k0 + row) * 1024 + n0 + cc];
  }
  __syncthreads();
  #pragma unroll
  for (int p = 0; p < 16; ++p) {
    int row = p * 4 + rr;                       // n offset
    dst[(size_t)(n0 + row) * 1024 + k0 + cc] = f2b(tile[cc][row]);
  }
}

// -------------------------------------------------------------- QKV GEMM
// C[4096,3072] = X[4096,1024] @ [wq|wk|wv] + bias. 128x128 block, BK=32, 4 waves.
// n<1024 -> Qb row-major bf16; <2048 -> Kb; else V^T [B][H][D][S] bf16.
__global__ __launch_bounds__(256, 2) void gemm_qkv_kernel(
    const unsigned short* __restrict__ X, const unsigned short* __restrict__ WT,
    const float* __restrict__ bq, const float* __restrict__ bk, const float* __restrict__ bv,
    unsigned short* __restrict__ Qb, unsigned short* __restrict__ Kb,
    unsigned short* __restrict__ VTo) {
  __shared__ unsigned short As[128 * 32];
  __shared__ unsigned short Bs[128 * 32];
  const int t = threadIdx.x, w = t >> 6, lane = t & 63;
  const int r = lane & 15, q4 = lane >> 4;
  const int m0 = blockIdx.y * 128, n0 = blockIdx.x * 128;
  const int wr = (w >> 1) * 64, wc = (w & 1) * 64;
  const unsigned short* Xg = X + (size_t)m0 * 1024;
  const unsigned short* Wg = WT + (size_t)n0 * 1024;
  f32x4 acc[4][4] = {};
  for (int k0 = 0; k0 < 1024; k0 += 32) {
    #pragma unroll
    for (int g = 0; g < 2; ++g) {
      int slot = g * 256 + t;                  // == g*256 + w*64 + lane
      int row = slot >> 2, ko = (slot & 3) * 8;
      GLD_LDS(Xg + (size_t)row * 1024 + k0 + ko, &As[(g * 256 + w * 64) * 8]);
      GLD_LDS(Wg + (size_t)row * 1024 + k0 + ko, &Bs[(g * 256 + w * 64) * 8]);
    }
    __syncthreads();
    bf16x8 af[4], bfr[4];
    #pragma unroll
    for (int mf = 0; mf < 4; ++mf)
      af[mf] = *(const bf16x8*)&As[(wr + mf * 16 + r) * 32 + q4 * 8];
    #pragma unroll
    for (int nf = 0; nf < 4; ++nf)
      bfr[nf] = *(const bf16x8*)&Bs[(wc + nf * 16 + r) * 32 + q4 * 8];
    #pragma unroll
    for (int mf = 0; mf < 4; ++mf)
      #pragma unroll
      for (int nf = 0; nf < 4; ++nf)
        acc[mf][nf] = __builtin_amdgcn_mfma_f32_16x16x32_bf16(af[mf], bfr[nf], acc[mf][nf], 0, 0, 0);
    __syncthreads();
  }
  // C/D layout (m89/m91): col = lane&15, row = (lane>>4)*4 + i
  const int nblk = n0 >> 10;
  if (nblk < 2) {
    const float* bias = (nblk == 0) ? bq : bk;
    unsigned short* OutB = (nblk == 0) ? Qb : Kb;
    const int nc0 = n0 & 1023;
    #pragma unroll
    for (int nf = 0; nf < 4; ++nf) {
      int n = nc0 + wc + nf * 16 + r;
      float bb = bias[n];
      #pragma unroll
      for (int mf = 0; mf < 4; ++mf) {
        int m = m0 + wr + mf * 16 + q4 * 4;
        f32x4 v = acc[mf][nf];
        #pragma unroll
        for (int i = 0; i < 4; ++i)
          OutB[(size_t)(m + i) * 1024 + n] = f2b(v[i] + bb);
      }
    }
  } else {
    const int c0 = n0 - 2048;
    #pragma unroll
    for (int nf = 0; nf < 4; ++nf) {
      int c = c0 + wc + nf * 16 + r;
      float bb = bv[c];
      int h = c >> 6, d = c & 63;
      #pragma unroll
      for (int mf = 0; mf < 4; ++mf) {
        int m = m0 + wr + mf * 16 + q4 * 4;
        int b = m >> 11, s = m & 2047;
        f32x4 v = acc[mf][nf];
        u16x4 pk;
        #pragma unroll
        for (int i = 0; i < 4; ++i) pk[i] = f2b(v[i] + bb);
        *(u16x4*)&VTo[((size_t)((b * 16 + h) * 64 + d)) * 2048 + s] = pk;  // 4 consecutive s
      }
    }
  }
}

// ---------------------------------------------------------------- sumsq
// qs2/ks2[(b*16+h)*2048+s] = ||Q||^2, ||K||^2 scaled by log2e/T
__global__ void sumsq_kernel(const unsigned short* __restrict__ Qb,
                             const unsigned short* __restrict__ Kb,
                             const float* __restrict__ temp,
                             float* __restrict__ qs2, float* __restrict__ ks2) {
  int idx = blockIdx.x * 256 + threadIdx.x;     // bh*2048 + s
  int bh = idx >> 11, s = idx & 2047;
  int b = bh >> 4, h = bh & 15;
  const unsigned short* qp = Qb + (size_t)(b * 2048 + s) * 1024 + h * 64;
  const unsigned short* kp = Kb + (size_t)(b * 2048 + s) * 1024 + h * 64;
  float scale = LOG2E / temp[0];
  float sq = 0.f, sk = 0.f;
  #pragma unroll
  for (int d = 0; d < 64; ++d) {
    float q = b2f(qp[d]); sq += q * q;
    float k = b2f(kp[d]); sk += k * k;
  }
  qs2[idx] = sq * scale;
  ks2[idx] = sk * scale;
}

// ---------------------------------------------------------------- flash
// One block = (bh, 128 q-rows); 4 waves x 32 rows. 64-key chunks.
// K LDS [half<2][key<64][dd<32]  (swizzled-linear so B-frag ds_read_b128 is conflict-free)
// V LDS [kh<2][d<64][kk<32]
// P per-wave LDS [32][72] (pad 8 -> 2-way banks, free per m136)
__global__ __launch_bounds__(256, 2) void flash_kernel(
    const unsigned short* __restrict__ Qb, const unsigned short* __restrict__ Kb,
    const unsigned short* __restrict__ VT, const float* __restrict__ qs2,
    const float* __restrict__ ks2, const float* __restrict__ temp,
    unsigned short* __restrict__ AO) {
  __shared__ unsigned short Ks[2 * 64 * 32];
  __shared__ unsigned short Vs[2 * 64 * 32];
  __shared__ unsigned short Ps[4][32 * 72];
  const int t = threadIdx.x, w = t >> 6, lane = t & 63;
  const int r = lane & 15, q4 = lane >> 4;
  const int bh = blockIdx.y, b = bh >> 4, h = bh & 15;
  const int q0 = blockIdx.x * 128;
  const float cc = 2.0f * LOG2E / temp[0];

  // Q fragments (A-layout: row=lane&15, k=(lane>>4)*8+j), resident in VGPRs
  bf16x8 qf[2][2];
  #pragma unroll
  for (int mf = 0; mf < 2; ++mf) {
    int sq = q0 + w * 32 + mf * 16 + r;
    const unsigned short* qp = Qb + (size_t)(b * 2048 + sq) * 1024 + h * 64;
    #pragma unroll
    for (int ks = 0; ks < 2; ++ks) qf[mf][ks] = *(const bf16x8*)(qp + ks * 32 + q4 * 8);
  }
  f32x4 qsv[2];
  #pragma unroll
  for (int mf = 0; mf < 2; ++mf)
    qsv[mf] = *(const f32x4*)&qs2[bh * 2048 + q0 + w * 32 + mf * 16 + q4 * 4];

  float mrun[2][4], lrun[2][4];
  #pragma unroll
  for (int mf = 0; mf < 2; ++mf)
    #pragma unroll
    for (int i = 0; i < 4; ++i) { mrun[mf][i] = -1e30f; lrun[mf][i] = 0.f; }
  f32x4 accO[2][4] = {};

  for (int key0 = 0; key0 < 2048; key0 += 64) {
    #pragma unroll
    for (int g = 0; g < 2; ++g) {
      int slot = g * 256 + t;
      int half = slot >> 8, key = (slot >> 2) & 63, ko = (slot & 3) * 8;
      GLD_LDS(Kb + (size_t)(b * 2048 + key0 + key) * 1024 + h * 64 + half * 32 + ko,
              &Ks[(g * 256 + w * 64) * 8]);
      int kh = slot >> 8, dd = (slot >> 2) & 63, kk = (slot & 3) * 8;
      GLD_LDS(VT + (size_t)(bh * 64 + dd) * 2048 + key0 + kh * 32 + kk,
              &Vs[(g * 256 + w * 64) * 8]);
    }
    __syncthreads();

    // S = Q K^T  (C: col=key via lane&15, rows q4*4+i)
    f32x4 accS[2][4] = {};
    #pragma unroll
    for (int nf = 0; nf < 4; ++nf) {
      int key = nf * 16 + r;
      #pragma unroll
      for (int ks = 0; ks < 2; ++ks) {
        bf16x8 kf = *(const bf16x8*)&Ks[(ks * 64 + key) * 32 + q4 * 8];
        accS[0][nf] = __builtin_amdgcn_mfma_f32_16x16x32_bf16(qf[0][ks], kf, accS[0][nf], 0, 0, 0);
        accS[1][nf] = __builtin_amdgcn_mfma_f32_16x16x32_bf16(qf[1][ks], kf, accS[1][nf], 0, 0, 0);
      }
    }
    float ksv[4];
    #pragma unroll
    for (int nf = 0; nf < 4; ++nf) ksv[nf] = ks2[bh * 2048 + key0 + nf * 16 + r];

    #pragma unroll
    for (int mf = 0; mf < 2; ++mf) {
      float sv[4][4];
      float mx[4] = {-1e30f, -1e30f, -1e30f, -1e30f};
      #pragma unroll
      for (int nf = 0; nf < 4; ++nf)
        #pragma unroll
        for (int i = 0; i < 4; ++i) {
          float s = fminf(cc * accS[mf][nf][i] - ksv[nf], qsv[mf][i]);  // min(2qk-k^2, q^2)*log2e/T
          sv[nf][i] = s;
          mx[i] = fmaxf(mx[i], s);
        }
      #pragma unroll
      for (int i = 0; i < 4; ++i) {           // row-max over the 16-lane col group
        float v = mx[i];
        v = fmaxf(v, __shfl_xor(v, 1, 64));
        v = fmaxf(v, __shfl_xor(v, 2, 64));
        v = fmaxf(v, __shfl_xor(v, 4, 64));
        v = fmaxf(v, __shfl_xor(v, 8, 64));
        mx[i] = v;
      }
      float al[4], rs[4];
      #pragma unroll
      for (int i = 0; i < 4; ++i) {
        float mn = fmaxf(mrun[mf][i], mx[i]);
        al[i] = exp2f(mrun[mf][i] - mn);
        mrun[mf][i] = mn;
        rs[i] = 0.f;
      }
      #pragma unroll
      for (int nf = 0; nf < 4; ++nf)
        #pragma unroll
        for (int i = 0; i < 4; ++i) {
          float p = exp2f(sv[nf][i] - mrun[mf][i]);
          sv[nf][i] = p;
          rs[i] += p;
        }
      #pragma unroll
      for (int i = 0; i < 4; ++i) {
        float v = rs[i];
        v += __shfl_xor(v, 1, 64);
        v += __shfl_xor(v, 2, 64);
        v += __shfl_xor(v, 4, 64);
        v += __shfl_xor(v, 8, 64);
        lrun[mf][i] = lrun[mf][i] * al[i] + v;
      }
      #pragma unroll
      for (int df = 0; df < 4; ++df)
        #pragma unroll
        for (int i = 0; i < 4; ++i) accO[mf][df][i] *= al[i];
      // P: C-layout -> LDS (A-layout round-trip, per-wave buffer)
      #pragma unroll
      for (int nf = 0; nf < 4; ++nf)
        #pragma unroll
        for (int i = 0; i < 4; ++i)
          Ps[w][(mf * 16 + q4 * 4 + i) * 72 + nf * 16 + r] = f2b(sv[nf][i]);
    }
    // O += P V
    #pragma unroll
    for (int ks = 0; ks < 2; ++ks) {
      bf16x8 vb[4];
      #pragma unroll
      for (int df = 0; df < 4; ++df)
        vb[df] = *(const bf16x8*)&Vs[(ks * 64 + df * 16 + r) * 32 + q4 * 8];
      #pragma unroll
      for (int mf = 0; mf < 2; ++mf) {
        bf16x8 pa = *(const bf16x8*)&Ps[w][(mf * 16 + r) * 72 + ks * 32 + q4 * 8];
        #pragma unroll
        for (int df = 0; df < 4; ++df)
          accO[mf][df] = __builtin_amdgcn_mfma_f32_16x16x32_bf16(pa, vb[df], accO[mf][df], 0, 0, 0);
      }
    }
    __syncthreads();
  }
  #pragma unroll
  for (int mf = 0; mf < 2; ++mf) {
    float inv[4];
    #pragma unroll
    for (int i = 0; i < 4; ++i) inv[i] = 1.0f / lrun[mf][i];
    #pragma unroll
    for (int df = 0; df < 4; ++df) {
      int d = df * 16 + r;
      #pragma unroll
      for (int i = 0; i < 4; ++i) {
        int sq = q0 + w * 32 + mf * 16 + q4 * 4 + i;
        AO[(size_t)(b * 2048 + sq) * 1024 + h * 64 + d] = f2b(accO[mf][df][i] * inv[i]);
      }
    }
  }
}

// ------------------------------------------------------------- out GEMM
__global__ __launch_bounds__(256, 2) void gemm_out_kernel(
    const unsigned short* __restrict__ A, const unsigned short* __restrict__ WT,
    const float* __restrict__ bo, float* __restrict__ Out) {
  __shared__ unsigned short As[128 * 32];
  __shared__ unsigned short Bs[128 * 32];
  const int t = threadIdx.x, w = t >> 6, lane = t & 63;
  const int r = lane & 15, q4 = lane >> 4;
  const int m0 = blockIdx.y * 128, n0 = blockIdx.x * 128;
  const int wr = (w >> 1) * 64, wc = (w & 1) * 64;
  const unsigned short* Ag = A + (size_t)m0 * 1024;
  const unsigned short* Wg = WT + (size_t)n0 * 1024;
  f32x4 acc[4][4] = {};
  for (int k0 = 0; k0 < 1024; k0 += 32) {
    #pragma unroll
    for (int g = 0; g < 2; ++g) {
      int slot = g * 256 + t;
      int row = slot >> 2, ko = (slot & 3) * 8;
      GLD_LDS(Ag + (size_t)row * 1024 + k0 + ko, &As[(g * 256 + w * 64) * 8]);
      GLD_LDS(Wg + (size_t)row * 1024 + k0 + ko, &Bs[(g * 256 + w * 64) * 8]);
    }
    __syncthreads();
    bf16x8 af[4], bfr[4];
    #pragma unroll
    for (int mf = 0; mf < 4; ++mf)
      af[mf] = *(const bf16x8*)&As[(wr + mf * 16 + r) * 32 + q4 * 8];
    #pragma unroll
    for (int nf = 0; nf < 4; ++nf)
      bfr[nf] = *(const bf16x8*)&Bs[(wc + nf * 16 + r) * 32 + q4 * 8];
    #pragma unroll
    for (int mf = 0; mf < 4; ++mf)
      #pragma unroll
      for (int nf = 0; nf < 4; ++nf)
        acc[mf][nf] = __builtin_amdgcn_mfma_f32_16x16x32_bf16(af[mf], bfr[nf], acc[mf][nf], 0, 0, 0);
    __syncthreads();
  }
  #pragma unroll
  for (int nf = 0; nf < 4; ++nf) {
    int n = n0 + wc + nf * 16 + r;
    float bb = bo[n];
    #pragma unroll
    for (int mf = 0; mf < 4; ++mf) {
      int m = m0 + wr + mf * 16 + q4 * 4;
      f32x4 v = acc[mf][nf];
      #pragma unroll
      for (int i = 0; i < 4; ++i)
        Out[(size_t)(m + i) * 1024 + n] = v[i] + bb;
    }
  }
}

// ---------------------------------------------------------------- launch
extern "C" void kernel_launch(void* const* d_in, const int* in_sizes, int n_in,
                              void* d_out, int out_size, void* d_ws, size_t ws_size,
                              hipStream_t stream) {
  const float* X    = (const float*)d_in[0];
  const float* wq   = (const float*)d_in[1];
  const float* bq   = (const float*)d_in[2];
  const float* wk   = (const float*)d_in[3];
  const float* bk   = (const float*)d_in[4];
  const float* wv   = (const float*)d_in[5];
  const float* bv   = (const float*)d_in[6];
  const float* wo   = (const float*)d_in[7];
  const float* bo   = (const float*)d_in[8];
  const float* temp = (const float*)d_in[9];
  float* Out = (float*)d_out;

  char* ws = (char*)d_ws;
  unsigned short* Xb    = (unsigned short*)ws; ws += (size_t)4096 * 1024 * 2;
  unsigned short* WTqkv = (unsigned short*)ws; ws += (size_t)3072 * 1024 * 2;
  unsigned short* WTo   = (unsigned short*)ws; ws += (size_t)1024 * 1024 * 2;
  unsigned short* Qb    = (unsigned short*)ws; ws += (size_t)4096 * 1024 * 2;
  unsigned short* Kb    = (unsigned short*)ws; ws += (size_t)4096 * 1024 * 2;
  unsigned short* VT    = (unsigned short*)ws; ws += (size_t)4096 * 1024 * 2;
  unsigned short* AO    = (unsigned short*)ws; ws += (size_t)4096 * 1024 * 2;
  float* qs2 = (float*)ws; ws += (size_t)65536 * 4;
  float* ks2 = (float*)ws; ws += (size_t)65536 * 4;

  convx_kernel<<<4096, 256, 0, stream>>>(X, Xb);
  transw_kernel<<<dim3(16, 16, 4), 256, 0, stream>>>(wq, wk, wv, wo, WTqkv, WTo);
  gemm_qkv_kernel<<<dim3(24, 32), 256, 0, stream>>>(Xb, WTqkv, bq, bk, bv, Qb, Kb, VT);
  sumsq_kernel<<<256, 256, 0, stream>>>(Qb, Kb, temp, qs2, ks2);
  flash_kernel<<<dim3(16, 32), 256, 0, stream>>>(Qb, Kb, VT, qs2, ks2, temp, AO);
  gemm_out_kernel<<<dim3(8, 32), 256, 0, stream>>>(AO, WTo, bo, Out);
}

// Round 2
// 222.053 us; speedup vs baseline: 1.3066x; 1.3066x over previous
//
#include <hip/hip_runtime.h>
#include <stdint.h>
#include <stddef.h>

// EuclideanAttention MI355X, round 2.
// Flash rewrite: no online softmax (shift = q^2 bound, exact), rowsum via
// ones-MFMA, conflict-free P stride 68, 128-key staged chunks.

#define LOG2E 1.44269504088896f

typedef __attribute__((ext_vector_type(8))) short bf16x8;
typedef __attribute__((ext_vector_type(4))) float f32x4;
typedef __attribute__((ext_vector_type(4))) unsigned short u16x4;
typedef __attribute__((ext_vector_type(8))) unsigned short u16x8;

__device__ __forceinline__ unsigned short f2b(float f) {
  union { float f; unsigned int u; } x; x.f = f;
  unsigned int u = x.u;
  u += 0x7fffu + ((u >> 16) & 1u);   // RNE
  return (unsigned short)(u >> 16);
}
__device__ __forceinline__ float b2f(unsigned short s) {
  union { unsigned int u; float f; } x; x.u = ((unsigned int)s) << 16;
  return x.f;
}

// async global->LDS, 16B per lane. LDS dest = uniform base + lane*16 (m104/m108).
#define GLD_LDS(g, l) __builtin_amdgcn_global_load_lds( \
    (const __attribute__((address_space(1))) void*)(g), \
    (__attribute__((address_space(3))) void*)(l), 16, 0, 0)

// ---------------------------------------------------------------- convX
__global__ void convx_kernel(const float* __restrict__ X, unsigned short* __restrict__ Xb) {
  int i = (blockIdx.x * 256 + threadIdx.x) * 4;
  f32x4 v = *(const f32x4*)&X[i];
  u16x4 o;
  #pragma unroll
  for (int j = 0; j < 4; ++j) o[j] = f2b(v[j]);
  *(u16x4*)&Xb[i] = o;
}

// ------------------------------------------------------------- transposeW
__global__ void transw_kernel(const float* __restrict__ wq, const float* __restrict__ wk,
                              const float* __restrict__ wv, const float* __restrict__ wo,
                              unsigned short* __restrict__ WTqkv, unsigned short* __restrict__ WTo) {
  __shared__ float tile[64][65];
  int z = blockIdx.z;
  const float* src = (z == 0) ? wq : (z == 1) ? wk : (z == 2) ? wv : wo;
  unsigned short* dst = (z < 3) ? (WTqkv + (size_t)z * 1024 * 1024) : WTo;
  int k0 = blockIdx.y * 64, n0 = blockIdx.x * 64;
  int rr = threadIdx.x >> 6, cc = threadIdx.x & 63;
  #pragma unroll
  for (int p = 0; p < 16; ++p) {
    int row = p * 4 + rr;
    tile[row][cc] = src[(size_t)(k0 + row) * 1024 + n0 + cc];
  }
  __syncthreads();
  #pragma unroll
  for (int p = 0; p < 16; ++p) {
    int row = p * 4 + rr;                       // n offset
    dst[(size_t)(n0 + row) * 1024 + k0 + cc] = f2b(tile[cc][row]);
  }
}

// -------------------------------------------------------------- QKV GEMM
// C[4096,3072] = X[4096,1024] @ [wq|wk|wv] + bias. 128x128 block, BK=32, 4 waves.
__global__ __launch_bounds__(256, 2) void gemm_qkv_kernel(
    const unsigned short* __restrict__ X, const unsigned short* __restrict__ WT,
    const float* __restrict__ bq, const float* __restrict__ bk, const float* __restrict__ bv,
    unsigned short* __restrict__ Qb, unsigned short* __restrict__ Kb,
    unsigned short* __restrict__ VTo) {
  __shared__ unsigned short As[128 * 32];
  __shared__ unsigned short Bs[128 * 32];
  const int t = threadIdx.x, w = t >> 6, lane = t & 63;
  const int r = lane & 15, q4 = lane >> 4;
  const int m0 = blockIdx.y * 128, n0 = blockIdx.x * 128;
  const int wr = (w >> 1) * 64, wc = (w & 1) * 64;
  const unsigned short* Xg = X + (size_t)m0 * 1024;
  const unsigned short* Wg = WT + (size_t)n0 * 1024;
  f32x4 acc[4][4] = {};
  for (int k0 = 0; k0 < 1024; k0 += 32) {
    #pragma unroll
    for (int g = 0; g < 2; ++g) {
      int slot = g * 256 + t;
      int row = slot >> 2, ko = (slot & 3) * 8;
      GLD_LDS(Xg + (size_t)row * 1024 + k0 + ko, &As[(g * 256 + w * 64) * 8]);
      GLD_LDS(Wg + (size_t)row * 1024 + k0 + ko, &Bs[(g * 256 + w * 64) * 8]);
    }
    __syncthreads();
    bf16x8 af[4], bfr[4];
    #pragma unroll
    for (int mf = 0; mf < 4; ++mf)
      af[mf] = *(const bf16x8*)&As[(wr + mf * 16 + r) * 32 + q4 * 8];
    #pragma unroll
    for (int nf = 0; nf < 4; ++nf)
      bfr[nf] = *(const bf16x8*)&Bs[(wc + nf * 16 + r) * 32 + q4 * 8];
    #pragma unroll
    for (int mf = 0; mf < 4; ++mf)
      #pragma unroll
      for (int nf = 0; nf < 4; ++nf)
        acc[mf][nf] = __builtin_amdgcn_mfma_f32_16x16x32_bf16(af[mf], bfr[nf], acc[mf][nf], 0, 0, 0);
    __syncthreads();
  }
  const int nblk = n0 >> 10;
  if (nblk < 2) {
    const float* bias = (nblk == 0) ? bq : bk;
    unsigned short* OutB = (nblk == 0) ? Qb : Kb;
    const int nc0 = n0 & 1023;
    #pragma unroll
    for (int nf = 0; nf < 4; ++nf) {
      int n = nc0 + wc + nf * 16 + r;
      float bb = bias[n];
      #pragma unroll
      for (int mf = 0; mf < 4; ++mf) {
        int m = m0 + wr + mf * 16 + q4 * 4;
        f32x4 v = acc[mf][nf];
        #pragma unroll
        for (int i = 0; i < 4; ++i)
          OutB[(size_t)(m + i) * 1024 + n] = f2b(v[i] + bb);
      }
    }
  } else {
    const int c0 = n0 - 2048;
    #pragma unroll
    for (int nf = 0; nf < 4; ++nf) {
      int c = c0 + wc + nf * 16 + r;
      float bb = bv[c];
      int h = c >> 6, d = c & 63;
      #pragma unroll
      for (int mf = 0; mf < 4; ++mf) {
        int m = m0 + wr + mf * 16 + q4 * 4;
        int b = m >> 11, s = m & 2047;
        f32x4 v = acc[mf][nf];
        u16x4 pk;
        #pragma unroll
        for (int i = 0; i < 4; ++i) pk[i] = f2b(v[i] + bb);
        *(u16x4*)&VTo[((size_t)((b * 16 + h) * 64 + d)) * 2048 + s] = pk;
      }
    }
  }
}

// ---------------------------------------------------------------- sumsq
// qs2/ks2[(b*16+h)*2048+s] = ||row||^2 * log2e/T, vectorized b128 loads.
__global__ void sumsq_kernel(const unsigned short* __restrict__ Qb,
                             const unsigned short* __restrict__ Kb,
                             const float* __restrict__ temp,
                             float* __restrict__ qs2, float* __restrict__ ks2) {
  int idx = blockIdx.x * 256 + threadIdx.x;     // bh*2048 + s
  int bh = idx >> 11, s = idx & 2047;
  int b = bh >> 4, h = bh & 15;
  const u16x8* qp = (const u16x8*)(Qb + (size_t)(b * 2048 + s) * 1024 + h * 64);
  const u16x8* kp = (const u16x8*)(Kb + (size_t)(b * 2048 + s) * 1024 + h * 64);
  float scale = LOG2E / temp[0];
  float sq = 0.f, sk = 0.f;
  #pragma unroll
  for (int c = 0; c < 8; ++c) {
    u16x8 vq = qp[c], vk = kp[c];
    #pragma unroll
    for (int j = 0; j < 8; ++j) {
      float q = b2f(vq[j]); sq += q * q;
      float k = b2f(vk[j]); sk += k * k;
    }
  }
  qs2[idx] = sq * scale;
  ks2[idx] = sk * scale;
}

// ---------------------------------------------------------------- flash
// One block = (bh, 128 q-rows); 4 waves x 32 rows; 128-key staged chunks,
// processed as two 64-key halves. No online max: shift = q^2*log2e/T (upper
// bound of scores) => p = exp2(min(2qk-k^2-q^2,0)*log2e/T), exact softmax
// numerator. Row sums via ones-MFMA into C-layout lsum.
__global__ __launch_bounds__(256, 2) void flash_kernel(
    const unsigned short* __restrict__ Qb, const unsigned short* __restrict__ Kb,
    const unsigned short* __restrict__ VT, const float* __restrict__ qs2,
    const float* __restrict__ ks2, const float* __restrict__ temp,
    unsigned short* __restrict__ AO) {
  __shared__ unsigned short Ks[2 * 128 * 32];   // 16 KB [half<2][key<128][dd<32]
  __shared__ unsigned short Vs[4 * 64 * 32];    // 16 KB [kh<4][d<64][kk<32]
  __shared__ unsigned short Ps[4][32 * 68];     // 17.4 KB per-wave P, stride 68 = conflict-free
  const int t = threadIdx.x, w = t >> 6, lane = t & 63;
  const int r = lane & 15, q4 = lane >> 4;
  const int bh = blockIdx.y, b = bh >> 4, h = bh & 15;
  const int q0 = blockIdx.x * 128;
  const float cc = 2.0f * LOG2E / temp[0];

  // Q fragments (A-layout: row=lane&15, k=(lane>>4)*8+j)
  bf16x8 qf[2][2];
  #pragma unroll
  for (int mf = 0; mf < 2; ++mf) {
    int sq = q0 + w * 32 + mf * 16 + r;
    const unsigned short* qp = Qb + (size_t)(b * 2048 + sq) * 1024 + h * 64;
    #pragma unroll
    for (int ks = 0; ks < 2; ++ks) qf[mf][ks] = *(const bf16x8*)(qp + ks * 32 + q4 * 8);
  }
  f32x4 qsv[2];
  #pragma unroll
  for (int mf = 0; mf < 2; ++mf)
    qsv[mf] = *(const f32x4*)&qs2[bh * 2048 + q0 + w * 32 + mf * 16 + q4 * 4];

  f32x4 accO[2][4] = {};
  f32x4 lsum[2] = {};
  bf16x8 ones;
  #pragma unroll
  for (int j = 0; j < 8; ++j) ones[j] = (short)0x3F80;   // bf16 1.0

  for (int key0 = 0; key0 < 2048; key0 += 128) {
    #pragma unroll
    for (int g = 0; g < 4; ++g) {
      int slot = g * 256 + t;
      int half = slot >> 9, key = (slot >> 2) & 127, ko = (slot & 3) * 8;
      GLD_LDS(Kb + (size_t)(b * 2048 + key0 + key) * 1024 + h * 64 + half * 32 + ko,
              &Ks[(g * 256 + w * 64) * 8]);
      int kh = slot >> 8, dd = (slot >> 2) & 63, kk = (slot & 3) * 8;
      GLD_LDS(VT + (size_t)(bh * 64 + dd) * 2048 + key0 + kh * 32 + kk,
              &Vs[(g * 256 + w * 64) * 8]);
    }
    // prefetch k^2 for this chunk before the barrier (overlaps drain)
    float ksv[8];
    #pragma unroll
    for (int j = 0; j < 8; ++j) ksv[j] = ks2[bh * 2048 + key0 + j * 16 + r];
    __syncthreads();

    #pragma unroll
    for (int hh = 0; hh < 2; ++hh) {
      // S = Q K^T (C: col=key=lane&15 group, row=q4*4+i)
      f32x4 accS[2][4] = {};
      #pragma unroll
      for (int ks = 0; ks < 2; ++ks) {
        #pragma unroll
        for (int nf = 0; nf < 4; ++nf) {
          bf16x8 kf = *(const bf16x8*)&Ks[(ks * 128 + hh * 64 + nf * 16 + r) * 32 + q4 * 8];
          accS[0][nf] = __builtin_amdgcn_mfma_f32_16x16x32_bf16(qf[0][ks], kf, accS[0][nf], 0, 0, 0);
          accS[1][nf] = __builtin_amdgcn_mfma_f32_16x16x32_bf16(qf[1][ks], kf, accS[1][nf], 0, 0, 0);
        }
      }
      // p = exp2(min(cc*qk - k^2s - q^2s, 0)); write to per-wave P buffer
      #pragma unroll
      for (int mf = 0; mf < 2; ++mf) {
        #pragma unroll
        for (int nf = 0; nf < 4; ++nf) {
          float kq = ksv[hh * 4 + nf];
          #pragma unroll
          for (int i = 0; i < 4; ++i) {
            float u = cc * accS[mf][nf][i] - kq - qsv[mf][i];
            float p = __builtin_amdgcn_exp2f(fminf(u, 0.f));
            Ps[w][(mf * 16 + q4 * 4 + i) * 68 + nf * 16 + r] = f2b(p);
          }
        }
      }
      // O += P V ; lsum += P @ ones
      #pragma unroll
      for (int ks = 0; ks < 2; ++ks) {
        bf16x8 vb[4];
        #pragma unroll
        for (int df = 0; df < 4; ++df)
          vb[df] = *(const bf16x8*)&Vs[((hh * 2 + ks) * 64 + df * 16 + r) * 32 + q4 * 8];
        #pragma unroll
        for (int mf = 0; mf < 2; ++mf) {
          bf16x8 pa = *(const bf16x8*)&Ps[w][(mf * 16 + r) * 68 + ks * 32 + q4 * 8];
          lsum[mf] = __builtin_amdgcn_mfma_f32_16x16x32_bf16(pa, ones, lsum[mf], 0, 0, 0);
          #pragma unroll
          for (int df = 0; df < 4; ++df)
            accO[mf][df] = __builtin_amdgcn_mfma_f32_16x16x32_bf16(pa, vb[df], accO[mf][df], 0, 0, 0);
        }
      }
    }
    __syncthreads();
  }
  #pragma unroll
  for (int mf = 0; mf < 2; ++mf) {
    float inv[4];
    #pragma unroll
    for (int i = 0; i < 4; ++i) inv[i] = 1.0f / lsum[mf][i];
    #pragma unroll
    for (int df = 0; df < 4; ++df) {
      int d = df * 16 + r;
      #pragma unroll
      for (int i = 0; i < 4; ++i) {
        int sq = q0 + w * 32 + mf * 16 + q4 * 4 + i;
        AO[(size_t)(b * 2048 + sq) * 1024 + h * 64 + d] = f2b(accO[mf][df][i] * inv[i]);
      }
    }
  }
}

// ------------------------------------------------------------- out GEMM
__global__ __launch_bounds__(256, 2) void gemm_out_kernel(
    const unsigned short* __restrict__ A, const unsigned short* __restrict__ WT,
    const float* __restrict__ bo, float* __restrict__ Out) {
  __shared__ unsigned short As[128 * 32];
  __shared__ unsigned short Bs[128 * 32];
  const int t = threadIdx.x, w = t >> 6, lane = t & 63;
  const int r = lane & 15, q4 = lane >> 4;
  const int m0 = blockIdx.y * 128, n0 = blockIdx.x * 128;
  const int wr = (w >> 1) * 64, wc = (w & 1) * 64;
  const unsigned short* Ag = A + (size_t)m0 * 1024;
  const unsigned short* Wg = WT + (size_t)n0 * 1024;
  f32x4 acc[4][4] = {};
  for (int k0 = 0; k0 < 1024; k0 += 32) {
    #pragma unroll
    for (int g = 0; g < 2; ++g) {
      int slot = g * 256 + t;
      int row = slot >> 2, ko = (slot & 3) * 8;
      GLD_LDS(Ag + (size_t)row * 1024 + k0 + ko, &As[(g * 256 + w * 64) * 8]);
      GLD_LDS(Wg + (size_t)row * 1024 + k0 + ko, &Bs[(g * 256 + w * 64) * 8]);
    }
    __syncthreads();
    bf16x8 af[4], bfr[4];
    #pragma unroll
    for (int mf = 0; mf < 4; ++mf)
      af[mf] = *(const bf16x8*)&As[(wr + mf * 16 + r) * 32 + q4 * 8];
    #pragma unroll
    for (int nf = 0; nf < 4; ++nf)
      bfr[nf] = *(const bf16x8*)&Bs[(wc + nf * 16 + r) * 32 + q4 * 8];
    #pragma unroll
    for (int mf = 0; mf < 4; ++mf)
      #pragma unroll
      for (int nf = 0; nf < 4; ++nf)
        acc[mf][nf] = __builtin_amdgcn_mfma_f32_16x16x32_bf16(af[mf], bfr[nf], acc[mf][nf], 0, 0, 0);
    __syncthreads();
  }
  #pragma unroll
  for (int nf = 0; nf < 4; ++nf) {
    int n = n0 + wc + nf * 16 + r;
    float bb = bo[n];
    #pragma unroll
    for (int mf = 0; mf < 4; ++mf) {
      int m = m0 + wr + mf * 16 + q4 * 4;
      f32x4 v = acc[mf][nf];
      #pragma unroll
      for (int i = 0; i < 4; ++i)
        Out[(size_t)(m + i) * 1024 + n] = v[i] + bb;
    }
  }
}

// ---------------------------------------------------------------- launch
extern "C" void kernel_launch(void* const* d_in, const int* in_sizes, int n_in,
                              void* d_out, int out_size, void* d_ws, size_t ws_size,
                              hipStream_t stream) {
  const float* X    = (const float*)d_in[0];
  const float* wq   = (const float*)d_in[1];
  const float* bq   = (const float*)d_in[2];
  const float* wk   = (const float*)d_in[3];
  const float* bk   = (const float*)d_in[4];
  const float* wv   = (const float*)d_in[5];
  const float* bv   = (const float*)d_in[6];
  const float* wo   = (const float*)d_in[7];
  const float* bo   = (const float*)d_in[8];
  const float* temp = (const float*)d_in[9];
  float* Out = (float*)d_out;

  char* ws = (char*)d_ws;
  unsigned short* Xb    = (unsigned short*)ws; ws += (size_t)4096 * 1024 * 2;
  unsigned short* WTqkv = (unsigned short*)ws; ws += (size_t)3072 * 1024 * 2;
  unsigned short* WTo   = (unsigned short*)ws; ws += (size_t)1024 * 1024 * 2;
  unsigned short* Qb    = (unsigned short*)ws; ws += (size_t)4096 * 1024 * 2;
  unsigned short* Kb    = (unsigned short*)ws; ws += (size_t)4096 * 1024 * 2;
  unsigned short* VT    = (unsigned short*)ws; ws += (size_t)4096 * 1024 * 2;
  unsigned short* AO    = (unsigned short*)ws; ws += (size_t)4096 * 1024 * 2;
  float* qs2 = (float*)ws; ws += (size_t)65536 * 4;
  float* ks2 = (float*)ws; ws += (size_t)65536 * 4;

  convx_kernel<<<4096, 256, 0, stream>>>(X, Xb);
  transw_kernel<<<dim3(16, 16, 4), 256, 0, stream>>>(wq, wk, wv, wo, WTqkv, WTo);
  gemm_qkv_kernel<<<dim3(24, 32), 256, 0, stream>>>(Xb, WTqkv, bq, bk, bv, Qb, Kb, VT);
  sumsq_kernel<<<256, 256, 0, stream>>>(Qb, Kb, temp, qs2, ks2);
  flash_kernel<<<dim3(16, 32), 256, 0, stream>>>(Qb, Kb, VT, qs2, ks2, temp, AO);
  gemm_out_kernel<<<dim3(8, 32), 256, 0, stream>>>(AO, WTo, bo, Out);
}

// Round 3
// 209.762 us; speedup vs baseline: 1.3831x; 1.0586x over previous
//
#include <hip/hip_runtime.h>
#include <stdint.h>
#include <stddef.h>

// EuclideanAttention MI355X, round 3.
// - flash: 64-key double-buffered chunks, loads prefetched across the barrier
//   (barrier placed BEFORE next stage-issue so vmcnt(0) drain is cheap),
//   truncating f2b for P.
// - GEMMs: BK=64 (two BK=32 sub-stages -> half the barriers);
//   gemm_out retiled 128x64 -> 512 blocks (2/CU).

#define LOG2E 1.44269504088896f

typedef __attribute__((ext_vector_type(8))) short bf16x8;
typedef __attribute__((ext_vector_type(4))) float f32x4;
typedef __attribute__((ext_vector_type(4))) unsigned short u16x4;
typedef __attribute__((ext_vector_type(8))) unsigned short u16x8;

__device__ __forceinline__ unsigned short f2b(float f) {
  union { float f; unsigned int u; } x; x.f = f;
  unsigned int u = x.u;
  u += 0x7fffu + ((u >> 16) & 1u);   // RNE
  return (unsigned short)(u >> 16);
}
__device__ __forceinline__ float b2f(unsigned short s) {
  union { unsigned int u; float f; } x; x.u = ((unsigned int)s) << 16;
  return x.f;
}

// async global->LDS, 16B per lane. LDS dest = wave-uniform base + lane*16.
#define GLD_LDS(g, l) __builtin_amdgcn_global_load_lds( \
    (const __attribute__((address_space(1))) void*)(g), \
    (__attribute__((address_space(3))) void*)(l), 16, 0, 0)

// ---------------------------------------------------------------- convX
__global__ void convx_kernel(const float* __restrict__ X, unsigned short* __restrict__ Xb) {
  int i = (blockIdx.x * 256 + threadIdx.x) * 4;
  f32x4 v = *(const f32x4*)&X[i];
  u16x4 o;
  #pragma unroll
  for (int j = 0; j < 4; ++j) o[j] = f2b(v[j]);
  *(u16x4*)&Xb[i] = o;
}

// ------------------------------------------------------------- transposeW
__global__ void transw_kernel(const float* __restrict__ wq, const float* __restrict__ wk,
                              const float* __restrict__ wv, const float* __restrict__ wo,
                              unsigned short* __restrict__ WTqkv, unsigned short* __restrict__ WTo) {
  __shared__ float tile[64][65];
  int z = blockIdx.z;
  const float* src = (z == 0) ? wq : (z == 1) ? wk : (z == 2) ? wv : wo;
  unsigned short* dst = (z < 3) ? (WTqkv + (size_t)z * 1024 * 1024) : WTo;
  int k0 = blockIdx.y * 64, n0 = blockIdx.x * 64;
  int rr = threadIdx.x >> 6, cc = threadIdx.x & 63;
  #pragma unroll
  for (int p = 0; p < 16; ++p) {
    int row = p * 4 + rr;
    tile[row][cc] = src[(size_t)(k0 + row) * 1024 + n0 + cc];
  }
  __syncthreads();
  #pragma unroll
  for (int p = 0; p < 16; ++p) {
    int row = p * 4 + rr;                       // n offset
    dst[(size_t)(n0 + row) * 1024 + k0 + cc] = f2b(tile[cc][row]);
  }
}

// -------------------------------------------------------------- QKV GEMM
// C[4096,3072] = X @ [wq|wk|wv] + bias. 128x128 block, BK=64 (2 sub-stages).
__global__ __launch_bounds__(256, 2) void gemm_qkv_kernel(
    const unsigned short* __restrict__ X, const unsigned short* __restrict__ WT,
    const float* __restrict__ bq, const float* __restrict__ bk, const float* __restrict__ bv,
    unsigned short* __restrict__ Qb, unsigned short* __restrict__ Kb,
    unsigned short* __restrict__ VTo) {
  __shared__ unsigned short As[2 * 128 * 32];   // [kh][row][32]
  __shared__ unsigned short Bs[2 * 128 * 32];
  const int t = threadIdx.x, w = t >> 6, lane = t & 63;
  const int r = lane & 15, q4 = lane >> 4;
  const int m0 = blockIdx.y * 128, n0 = blockIdx.x * 128;
  const int wr = (w >> 1) * 64, wc = (w & 1) * 64;
  const unsigned short* Xg = X + (size_t)m0 * 1024;
  const unsigned short* Wg = WT + (size_t)n0 * 1024;
  f32x4 acc[4][4] = {};
  for (int k0 = 0; k0 < 1024; k0 += 64) {
    #pragma unroll
    for (int g = 0; g < 4; ++g) {
      int slot = g * 256 + t;
      int kh = slot >> 9, row = (slot >> 2) & 127, ko = (slot & 3) * 8;
      GLD_LDS(Xg + (size_t)row * 1024 + k0 + kh * 32 + ko, &As[(g * 256 + w * 64) * 8]);
      GLD_LDS(Wg + (size_t)row * 1024 + k0 + kh * 32 + ko, &Bs[(g * 256 + w * 64) * 8]);
    }
    __syncthreads();
    #pragma unroll
    for (int kh = 0; kh < 2; ++kh) {
      bf16x8 af[4], bfr[4];
      #pragma unroll
      for (int mf = 0; mf < 4; ++mf)
        af[mf] = *(const bf16x8*)&As[kh * 4096 + (wr + mf * 16 + r) * 32 + q4 * 8];
      #pragma unroll
      for (int nf = 0; nf < 4; ++nf)
        bfr[nf] = *(const bf16x8*)&Bs[kh * 4096 + (wc + nf * 16 + r) * 32 + q4 * 8];
      #pragma unroll
      for (int mf = 0; mf < 4; ++mf)
        #pragma unroll
        for (int nf = 0; nf < 4; ++nf)
          acc[mf][nf] = __builtin_amdgcn_mfma_f32_16x16x32_bf16(af[mf], bfr[nf], acc[mf][nf], 0, 0, 0);
    }
    __syncthreads();
  }
  const int nblk = n0 >> 10;
  if (nblk < 2) {
    const float* bias = (nblk == 0) ? bq : bk;
    unsigned short* OutB = (nblk == 0) ? Qb : Kb;
    const int nc0 = n0 & 1023;
    #pragma unroll
    for (int nf = 0; nf < 4; ++nf) {
      int n = nc0 + wc + nf * 16 + r;
      float bb = bias[n];
      #pragma unroll
      for (int mf = 0; mf < 4; ++mf) {
        int m = m0 + wr + mf * 16 + q4 * 4;
        f32x4 v = acc[mf][nf];
        #pragma unroll
        for (int i = 0; i < 4; ++i)
          OutB[(size_t)(m + i) * 1024 + n] = f2b(v[i] + bb);
      }
    }
  } else {
    const int c0 = n0 - 2048;
    #pragma unroll
    for (int nf = 0; nf < 4; ++nf) {
      int c = c0 + wc + nf * 16 + r;
      float bb = bv[c];
      int h = c >> 6, d = c & 63;
      #pragma unroll
      for (int mf = 0; mf < 4; ++mf) {
        int m = m0 + wr + mf * 16 + q4 * 4;
        int b = m >> 11, s = m & 2047;
        f32x4 v = acc[mf][nf];
        u16x4 pk;
        #pragma unroll
        for (int i = 0; i < 4; ++i) pk[i] = f2b(v[i] + bb);
        *(u16x4*)&VTo[((size_t)((b * 16 + h) * 64 + d)) * 2048 + s] = pk;
      }
    }
  }
}

// ---------------------------------------------------------------- sumsq
__global__ void sumsq_kernel(const unsigned short* __restrict__ Qb,
                             const unsigned short* __restrict__ Kb,
                             const float* __restrict__ temp,
                             float* __restrict__ qs2, float* __restrict__ ks2) {
  int idx = blockIdx.x * 256 + threadIdx.x;     // bh*2048 + s
  int bh = idx >> 11, s = idx & 2047;
  int b = bh >> 4, h = bh & 15;
  const u16x8* qp = (const u16x8*)(Qb + (size_t)(b * 2048 + s) * 1024 + h * 64);
  const u16x8* kp = (const u16x8*)(Kb + (size_t)(b * 2048 + s) * 1024 + h * 64);
  float scale = LOG2E / temp[0];
  float sq = 0.f, sk = 0.f;
  #pragma unroll
  for (int c = 0; c < 8; ++c) {
    u16x8 vq = qp[c], vk = kp[c];
    #pragma unroll
    for (int j = 0; j < 8; ++j) {
      float q = b2f(vq[j]); sq += q * q;
      float k = b2f(vk[j]); sk += k * k;
    }
  }
  qs2[idx] = sq * scale;
  ks2[idx] = sk * scale;
}

// ---------------------------------------------------------------- flash
// Block = (bh, 128 q-rows), 4 waves x 32 rows. 64-key chunks, double-buffered
// K/V staging: barrier -> issue stage(c+1) -> compute(c); the vmcnt(0) drain
// at the next barrier covers loads that flew during a full compute phase.
// p = exp2(min(2qk - k^2 - q^2, 0)*log2e/T) exactly = softmax numerator
// (shift = per-row upper bound q^2); rowsum via ones-MFMA. P stored truncated.
__global__ __launch_bounds__(256, 2) void flash_kernel(
    const unsigned short* __restrict__ Qb, const unsigned short* __restrict__ Kb,
    const unsigned short* __restrict__ VT, const float* __restrict__ qs2,
    const float* __restrict__ ks2, const float* __restrict__ temp,
    unsigned short* __restrict__ AO) {
  __shared__ unsigned short Ks[2][2 * 64 * 32];   // [buf][half<2][key<64][32]
  __shared__ unsigned short Vs[2][2 * 64 * 32];   // [buf][kh<2][d<64][kk<32]
  __shared__ unsigned short Ps[4][32 * 68];       // per-wave P, stride 68
  const int t = threadIdx.x, w = t >> 6, lane = t & 63;
  const int r = lane & 15, q4 = lane >> 4;
  const int bh = blockIdx.y, b = bh >> 4, h = bh & 15;
  const int q0 = blockIdx.x * 128;
  const float cc = 2.0f * LOG2E / temp[0];

  // Q fragments (A-layout), resident in VGPRs
  bf16x8 qf[2][2];
  #pragma unroll
  for (int mf = 0; mf < 2; ++mf) {
    int sq = q0 + w * 32 + mf * 16 + r;
    const unsigned short* qp = Qb + (size_t)(b * 2048 + sq) * 1024 + h * 64;
    #pragma unroll
    for (int ks = 0; ks < 2; ++ks) qf[mf][ks] = *(const bf16x8*)(qp + ks * 32 + q4 * 8);
  }
  f32x4 qsv[2];
  #pragma unroll
  for (int mf = 0; mf < 2; ++mf)
    qsv[mf] = *(const f32x4*)&qs2[bh * 2048 + q0 + w * 32 + mf * 16 + q4 * 4];

  f32x4 accO[2][4] = {};
  f32x4 lsum[2] = {};
  bf16x8 ones;
  #pragma unroll
  for (int j = 0; j < 8; ++j) ones[j] = (short)0x3F80;   // bf16 1.0

  const unsigned short* Kg = Kb + ((size_t)b * 2048) * 1024 + h * 64;
  const unsigned short* Vg = VT + ((size_t)bh * 64) * 2048;
  const float* kqb = ks2 + bh * 2048 + r;

  // stage chunk 0 into buf 0
  #pragma unroll
  for (int g = 0; g < 2; ++g) {
    int slot = g * 256 + t;
    int half = slot >> 8, key = (slot >> 2) & 63, ko = (slot & 3) * 8;
    GLD_LDS(Kg + (size_t)key * 1024 + half * 32 + ko, &Ks[0][(g * 256 + w * 64) * 8]);
    GLD_LDS(Vg + (size_t)key * 2048 + half * 32 + ko, &Vs[0][(g * 256 + w * 64) * 8]);
  }
  float kq[4];
  #pragma unroll
  for (int nf = 0; nf < 4; ++nf) kq[nf] = kqb[nf * 16];

  #pragma unroll 2
  for (int c = 0; c < 32; ++c) {
    const int buf = c & 1;
    __syncthreads();                    // drains stage(c) (in flight during compute(c-1))
    float kqn[4];
    if (c < 31) {
      #pragma unroll
      for (int g = 0; g < 2; ++g) {
        int slot = g * 256 + t;
        int half = slot >> 8, key = (slot >> 2) & 63, ko = (slot & 3) * 8;
        GLD_LDS(Kg + (size_t)((c + 1) * 64 + key) * 1024 + half * 32 + ko,
                &Ks[buf ^ 1][(g * 256 + w * 64) * 8]);
        GLD_LDS(Vg + (size_t)key * 2048 + (c + 1) * 64 + half * 32 + ko,
                &Vs[buf ^ 1][(g * 256 + w * 64) * 8]);
      }
      #pragma unroll
      for (int nf = 0; nf < 4; ++nf) kqn[nf] = kqb[(c + 1) * 64 + nf * 16];
    }

    // S = Q K^T (C-layout: col=key group lane&15, rows q4*4+i)
    f32x4 accS[2][4] = {};
    #pragma unroll
    for (int ks = 0; ks < 2; ++ks) {
      #pragma unroll
      for (int nf = 0; nf < 4; ++nf) {
        bf16x8 kf = *(const bf16x8*)&Ks[buf][(ks * 64 + nf * 16 + r) * 32 + q4 * 8];
        accS[0][nf] = __builtin_amdgcn_mfma_f32_16x16x32_bf16(qf[0][ks], kf, accS[0][nf], 0, 0, 0);
        accS[1][nf] = __builtin_amdgcn_mfma_f32_16x16x32_bf16(qf[1][ks], kf, accS[1][nf], 0, 0, 0);
      }
    }
    // p = exp2(min(cc*qk - k2 - q2, 0)); truncating bf16 store to per-wave P
    #pragma unroll
    for (int mf = 0; mf < 2; ++mf) {
      #pragma unroll
      for (int nf = 0; nf < 4; ++nf) {
        #pragma unroll
        for (int i = 0; i < 4; ++i) {
          float u = __builtin_fmaf(cc, accS[mf][nf][i], -kq[nf] - qsv[mf][i]);
          float p = __builtin_amdgcn_exp2f(fminf(u, 0.f));
          union { float f; unsigned int u; } pu; pu.f = p;
          Ps[w][(mf * 16 + q4 * 4 + i) * 68 + nf * 16 + r] = (unsigned short)(pu.u >> 16);
        }
      }
    }
    // O += P V ; lsum += P @ ones
    #pragma unroll
    for (int ks = 0; ks < 2; ++ks) {
      bf16x8 vb[4];
      #pragma unroll
      for (int df = 0; df < 4; ++df)
        vb[df] = *(const bf16x8*)&Vs[buf][(ks * 64 + df * 16 + r) * 32 + q4 * 8];
      #pragma unroll
      for (int mf = 0; mf < 2; ++mf) {
        bf16x8 pa = *(const bf16x8*)&Ps[w][(mf * 16 + r) * 68 + ks * 32 + q4 * 8];
        lsum[mf] = __builtin_amdgcn_mfma_f32_16x16x32_bf16(pa, ones, lsum[mf], 0, 0, 0);
        #pragma unroll
        for (int df = 0; df < 4; ++df)
          accO[mf][df] = __builtin_amdgcn_mfma_f32_16x16x32_bf16(pa, vb[df], accO[mf][df], 0, 0, 0);
      }
    }
    if (c < 31) {
      #pragma unroll
      for (int nf = 0; nf < 4; ++nf) kq[nf] = kqn[nf];
    }
  }
  #pragma unroll
  for (int mf = 0; mf < 2; ++mf) {
    float inv[4];
    #pragma unroll
    for (int i = 0; i < 4; ++i) inv[i] = 1.0f / lsum[mf][i];
    #pragma unroll
    for (int df = 0; df < 4; ++df) {
      int d = df * 16 + r;
      #pragma unroll
      for (int i = 0; i < 4; ++i) {
        int sq = q0 + w * 32 + mf * 16 + q4 * 4 + i;
        AO[(size_t)(b * 2048 + sq) * 1024 + h * 64 + d] = f2b(accO[mf][df][i] * inv[i]);
      }
    }
  }
}

// ------------------------------------------------------------- out GEMM
// 128x64 tile, BK=64, grid 16x32 = 512 blocks (2/CU). Waves 2x2: 64m x 32n.
__global__ __launch_bounds__(256, 2) void gemm_out_kernel(
    const unsigned short* __restrict__ A, const unsigned short* __restrict__ WT,
    const float* __restrict__ bo, float* __restrict__ Out) {
  __shared__ unsigned short As[2 * 128 * 32];   // [kh][row<128][32]
  __shared__ unsigned short Bs[2 * 64 * 32];    // [kh][row<64][32]
  const int t = threadIdx.x, w = t >> 6, lane = t & 63;
  const int r = lane & 15, q4 = lane >> 4;
  const int m0 = blockIdx.y * 128, n0 = blockIdx.x * 64;
  const int wr = (w >> 1) * 64, wc = (w & 1) * 32;
  const unsigned short* Ag = A + (size_t)m0 * 1024;
  const unsigned short* Wg = WT + (size_t)n0 * 1024;
  f32x4 acc[4][2] = {};
  for (int k0 = 0; k0 < 1024; k0 += 64) {
    #pragma unroll
    for (int g = 0; g < 4; ++g) {
      int slot = g * 256 + t;
      int kh = slot >> 9, row = (slot >> 2) & 127, ko = (slot & 3) * 8;
      GLD_LDS(Ag + (size_t)row * 1024 + k0 + kh * 32 + ko, &As[(g * 256 + w * 64) * 8]);
    }
    #pragma unroll
    for (int g = 0; g < 2; ++g) {
      int slot = g * 256 + t;
      int kh = slot >> 8, row = (slot >> 2) & 63, ko = (slot & 3) * 8;
      GLD_LDS(Wg + (size_t)row * 1024 + k0 + kh * 32 + ko, &Bs[(g * 256 + w * 64) * 8]);
    }
    __syncthreads();
    #pragma unroll
    for (int kh = 0; kh < 2; ++kh) {
      bf16x8 af[4], bfr[2];
      #pragma unroll
      for (int mf = 0; mf < 4; ++mf)
        af[mf] = *(const bf16x8*)&As[kh * 4096 + (wr + mf * 16 + r) * 32 + q4 * 8];
      #pragma unroll
      for (int nf = 0; nf < 2; ++nf)
        bfr[nf] = *(const bf16x8*)&Bs[kh * 2048 + (wc + nf * 16 + r) * 32 + q4 * 8];
      #pragma unroll
      for (int mf = 0; mf < 4; ++mf)
        #pragma unroll
        for (int nf = 0; nf < 2; ++nf)
          acc[mf][nf] = __builtin_amdgcn_mfma_f32_16x16x32_bf16(af[mf], bfr[nf], acc[mf][nf], 0, 0, 0);
    }
    __syncthreads();
  }
  #pragma unroll
  for (int nf = 0; nf < 2; ++nf) {
    int n = n0 + wc + nf * 16 + r;
    float bb = bo[n];
    #pragma unroll
    for (int mf = 0; mf < 4; ++mf) {
      int m = m0 + wr + mf * 16 + q4 * 4;
      f32x4 v = acc[mf][nf];
      #pragma unroll
      for (int i = 0; i < 4; ++i)
        Out[(size_t)(m + i) * 1024 + n] = v[i] + bb;
    }
  }
}

// ---------------------------------------------------------------- launch
extern "C" void kernel_launch(void* const* d_in, const int* in_sizes, int n_in,
                              void* d_out, int out_size, void* d_ws, size_t ws_size,
                              hipStream_t stream) {
  const float* X    = (const float*)d_in[0];
  const float* wq   = (const float*)d_in[1];
  const float* bq   = (const float*)d_in[2];
  const float* wk   = (const float*)d_in[3];
  const float* bk   = (const float*)d_in[4];
  const float* wv   = (const float*)d_in[5];
  const float* bv   = (const float*)d_in[6];
  const float* wo   = (const float*)d_in[7];
  const float* bo   = (const float*)d_in[8];
  const float* temp = (const float*)d_in[9];
  float* Out = (float*)d_out;

  char* ws = (char*)d_ws;
  unsigned short* Xb    = (unsigned short*)ws; ws += (size_t)4096 * 1024 * 2;
  unsigned short* WTqkv = (unsigned short*)ws; ws += (size_t)3072 * 1024 * 2;
  unsigned short* WTo   = (unsigned short*)ws; ws += (size_t)1024 * 1024 * 2;
  unsigned short* Qb    = (unsigned short*)ws; ws += (size_t)4096 * 1024 * 2;
  unsigned short* Kb    = (unsigned short*)ws; ws += (size_t)4096 * 1024 * 2;
  unsigned short* VT    = (unsigned short*)ws; ws += (size_t)4096 * 1024 * 2;
  unsigned short* AO    = (unsigned short*)ws; ws += (size_t)4096 * 1024 * 2;
  float* qs2 = (float*)ws; ws += (size_t)65536 * 4;
  float* ks2 = (float*)ws; ws += (size_t)65536 * 4;

  convx_kernel<<<4096, 256, 0, stream>>>(X, Xb);
  transw_kernel<<<dim3(16, 16, 4), 256, 0, stream>>>(wq, wk, wv, wo, WTqkv, WTo);
  gemm_qkv_kernel<<<dim3(24, 32), 256, 0, stream>>>(Xb, WTqkv, bq, bk, bv, Qb, Kb, VT);
  sumsq_kernel<<<256, 256, 0, stream>>>(Qb, Kb, temp, qs2, ks2);
  flash_kernel<<<dim3(16, 32), 256, 0, stream>>>(Qb, Kb, VT, qs2, ks2, temp, AO);
  gemm_out_kernel<<<dim3(16, 32), 256, 0, stream>>>(AO, WTo, bo, Out);
}

// Round 4
// 208.485 us; speedup vs baseline: 1.3916x; 1.0061x over previous
//
#include <hip/hip_runtime.h>
#include <stdint.h>
#include <stddef.h>

// EuclideanAttention MI355X, round 4.
// - flash: compute S^T = K.Q^T so the P fragments are produced directly in
//   PV A-operand layout (lane-local C->A identity under a permuted contraction
//   index) -- the P LDS round-trip is GONE. V staged via XOR-swizzled 16B
//   units so the paired ds_read_b64 B-frag reads are conflict-free.
// - sumsq fused into gemm_qkv epilogue (head cols fit inside one 128-tile).
// - convX merged into the W-transpose launch; gemm_qkv at 3 blocks/CU.

#define LOG2E 1.44269504088896f

typedef __attribute__((ext_vector_type(8))) short bf16x8;
typedef __attribute__((ext_vector_type(4))) short bf16x4;
typedef __attribute__((ext_vector_type(4))) float f32x4;
typedef __attribute__((ext_vector_type(4))) unsigned short u16x4;

__device__ __forceinline__ unsigned short f2b(float f) {
  union { float f; unsigned int u; } x; x.f = f;
  unsigned int u = x.u;
  u += 0x7fffu + ((u >> 16) & 1u);   // RNE
  return (unsigned short)(u >> 16);
}
__device__ __forceinline__ float b2f(unsigned short s) {
  union { unsigned int u; float f; } x; x.u = ((unsigned int)s) << 16;
  return x.f;
}
__device__ __forceinline__ unsigned int fbits(float f) {
  union { float f; unsigned int u; } x; x.f = f; return x.u;
}

// async global->LDS, 16B per lane. LDS dest = wave-uniform base + lane*16.
#define GLD_LDS(g, l) __builtin_amdgcn_global_load_lds( \
    (const __attribute__((address_space(1))) void*)(g), \
    (__attribute__((address_space(3))) void*)(l), 16, 0, 0)

// ------------------------------------------------- prep: W transpose + X cvt
// z<4: W [k][n] fp32 -> WT [n][k] bf16 (64x64 tiles). z==4: X fp32 -> bf16.
__global__ void prep_kernel(const float* __restrict__ X,
                            const float* __restrict__ wq, const float* __restrict__ wk,
                            const float* __restrict__ wv, const float* __restrict__ wo,
                            unsigned short* __restrict__ Xb,
                            unsigned short* __restrict__ WTqkv, unsigned short* __restrict__ WTo) {
  int z = blockIdx.z;
  if (z == 4) {
    size_t base = ((size_t)(blockIdx.y * 16 + blockIdx.x)) * 16384;
    #pragma unroll
    for (int j = 0; j < 16; ++j) {
      size_t i = base + (size_t)(j * 256 + threadIdx.x) * 4;
      f32x4 v = *(const f32x4*)&X[i];
      u16x4 o;
      #pragma unroll
      for (int k = 0; k < 4; ++k) o[k] = f2b(v[k]);
      *(u16x4*)&Xb[i] = o;
    }
    return;
  }
  __shared__ float tile[64][65];
  const float* src = (z == 0) ? wq : (z == 1) ? wk : (z == 2) ? wv : wo;
  unsigned short* dst = (z < 3) ? (WTqkv + (size_t)z * 1024 * 1024) : WTo;
  int k0 = blockIdx.y * 64, n0 = blockIdx.x * 64;
  int rr = threadIdx.x >> 6, cc = threadIdx.x & 63;
  #pragma unroll
  for (int p = 0; p < 16; ++p) {
    int row = p * 4 + rr;
    tile[row][cc] = src[(size_t)(k0 + row) * 1024 + n0 + cc];
  }
  __syncthreads();
  #pragma unroll
  for (int p = 0; p < 16; ++p) {
    int row = p * 4 + rr;                       // n offset
    dst[(size_t)(n0 + row) * 1024 + k0 + cc] = f2b(tile[cc][row]);
  }
}

// -------------------------------------------------------------- QKV GEMM
// C[4096,3072] = X @ [wq|wk|wv] + bias. 128x128 tile, BK=64. 768 blocks,
// 3 blocks/CU (one full round). Q/K epilogue also emits ||row||^2 per head
// (head's 64 cols are wave-local: wc half = one head).
__global__ __launch_bounds__(256, 3) void gemm_qkv_kernel(
    const unsigned short* __restrict__ X, const unsigned short* __restrict__ WT,
    const float* __restrict__ bq, const float* __restrict__ bk, const float* __restrict__ bv,
    unsigned short* __restrict__ Qb, unsigned short* __restrict__ Kb,
    unsigned short* __restrict__ VTo, float* __restrict__ qs2, float* __restrict__ ks2) {
  __shared__ unsigned short As[2 * 128 * 32];   // [kh][row][32]
  __shared__ unsigned short Bs[2 * 128 * 32];
  const int t = threadIdx.x, w = t >> 6, lane = t & 63;
  const int r = lane & 15, q4 = lane >> 4;
  const int m0 = blockIdx.y * 128, n0 = blockIdx.x * 128;
  const int wr = (w >> 1) * 64, wc = (w & 1) * 64;
  const unsigned short* Xg = X + (size_t)m0 * 1024;
  const unsigned short* Wg = WT + (size_t)n0 * 1024;
  f32x4 acc[4][4] = {};
  for (int k0 = 0; k0 < 1024; k0 += 64) {
    #pragma unroll
    for (int g = 0; g < 4; ++g) {
      int slot = g * 256 + t;
      int kh = slot >> 9, row = (slot >> 2) & 127, ko = (slot & 3) * 8;
      GLD_LDS(Xg + (size_t)row * 1024 + k0 + kh * 32 + ko, &As[(g * 256 + w * 64) * 8]);
      GLD_LDS(Wg + (size_t)row * 1024 + k0 + kh * 32 + ko, &Bs[(g * 256 + w * 64) * 8]);
    }
    __syncthreads();
    #pragma unroll
    for (int kh = 0; kh < 2; ++kh) {
      bf16x8 af[4], bfr[4];
      #pragma unroll
      for (int mf = 0; mf < 4; ++mf)
        af[mf] = *(const bf16x8*)&As[kh * 4096 + (wr + mf * 16 + r) * 32 + q4 * 8];
      #pragma unroll
      for (int nf = 0; nf < 4; ++nf)
        bfr[nf] = *(const bf16x8*)&Bs[kh * 4096 + (wc + nf * 16 + r) * 32 + q4 * 8];
      #pragma unroll
      for (int mf = 0; mf < 4; ++mf)
        #pragma unroll
        for (int nf = 0; nf < 4; ++nf)
          acc[mf][nf] = __builtin_amdgcn_mfma_f32_16x16x32_bf16(af[mf], bfr[nf], acc[mf][nf], 0, 0, 0);
    }
    __syncthreads();
  }
  const int nblk = n0 >> 10;
  if (nblk < 2) {
    const float* bias = (nblk == 0) ? bq : bk;
    unsigned short* OutB = (nblk == 0) ? Qb : Kb;
    float* S2 = (nblk == 0) ? qs2 : ks2;
    const int nc0 = n0 & 1023;
    float s2a[4][4] = {};
    #pragma unroll
    for (int nf = 0; nf < 4; ++nf) {
      int n = nc0 + wc + nf * 16 + r;
      float bb = bias[n];
      #pragma unroll
      for (int mf = 0; mf < 4; ++mf) {
        int m = m0 + wr + mf * 16 + q4 * 4;
        f32x4 v = acc[mf][nf];
        #pragma unroll
        for (int i = 0; i < 4; ++i) {
          unsigned short os = f2b(v[i] + bb);
          OutB[(size_t)(m + i) * 1024 + n] = os;
          float xb = b2f(os);
          s2a[mf][i] += xb * xb;          // sum of squares of the ROUNDED value
        }
      }
    }
    #pragma unroll
    for (int mf = 0; mf < 4; ++mf)
      #pragma unroll
      for (int i = 0; i < 4; ++i) {
        float v = s2a[mf][i];
        v += __shfl_xor(v, 1, 64);
        v += __shfl_xor(v, 2, 64);
        v += __shfl_xor(v, 4, 64);
        v += __shfl_xor(v, 8, 64);
        s2a[mf][i] = v;
      }
    if (r == 0) {
      int hh = (nc0 + wc) >> 6;
      #pragma unroll
      for (int mf = 0; mf < 4; ++mf) {
        int m = m0 + wr + mf * 16 + q4 * 4;
        int bb2 = m >> 11, ss = m & 2047;
        #pragma unroll
        for (int i = 0; i < 4; ++i)
          S2[(size_t)(bb2 * 16 + hh) * 2048 + ss + i] = s2a[mf][i];
      }
    }
  } else {
    const int c0 = n0 - 2048;
    #pragma unroll
    for (int nf = 0; nf < 4; ++nf) {
      int c = c0 + wc + nf * 16 + r;
      float bb = bv[c];
      int h = c >> 6, d = c & 63;
      #pragma unroll
      for (int mf = 0; mf < 4; ++mf) {
        int m = m0 + wr + mf * 16 + q4 * 4;
        int b = m >> 11, s = m & 2047;
        f32x4 v = acc[mf][nf];
        u16x4 pk;
        #pragma unroll
        for (int i = 0; i < 4; ++i) pk[i] = f2b(v[i] + bb);
        *(u16x4*)&VTo[((size_t)((b * 16 + h) * 64 + d)) * 2048 + s] = pk;
      }
    }
  }
}

// ---------------------------------------------------------------- flash
// Block = (bh, 128 q-rows), 4 waves x 32 rows, 64-key double-buffered chunks.
// S^T = K.Q^T: C-frag (col=qrow, row=key) doubles as the PV A-operand under
// contraction index tau(8*q4+j) = 32*cb + 4*q4 + j (+16 for j>=4) -- P stays
// in registers. V staged XOR-swizzled: 16B unit (d, gg) at slot d*8+(gg^(d&7)),
// so B-frag pair-b64 reads hit 4 dwords/bank (conflict-free).
// p = exp2(min(2qk - k2 - q2, 0)*log2e/T) (exact numerator); rowsum via ones.
__global__ __launch_bounds__(256, 2) void flash_kernel(
    const unsigned short* __restrict__ Qb, const unsigned short* __restrict__ Kb,
    const unsigned short* __restrict__ VT, const float* __restrict__ qs2,
    const float* __restrict__ ks2, const float* __restrict__ temp,
    unsigned short* __restrict__ AO) {
  __shared__ unsigned short Ks[2][64 * 64];   // [buf][half<2][key<64][dd<32]
  __shared__ unsigned short Vs[2][64 * 64];   // [buf] swizzled 16B units
  const int t = threadIdx.x, w = t >> 6, lane = t & 63;
  const int r = lane & 15, q4 = lane >> 4;
  const int bh = blockIdx.y, b = bh >> 4, h = bh & 15;
  const int q0 = blockIdx.x * 128;
  const float scale = LOG2E / temp[0];
  const float cc = 2.0f * scale;

  // Q fragments (B-operand: n=qrow=lane&15, k=q4*8+j)
  bf16x8 qf[2][2];
  #pragma unroll
  for (int mf = 0; mf < 2; ++mf) {
    int sq = q0 + w * 32 + mf * 16 + r;
    const unsigned short* qp = Qb + (size_t)(b * 2048 + sq) * 1024 + h * 64;
    #pragma unroll
    for (int ks = 0; ks < 2; ++ks) qf[mf][ks] = *(const bf16x8*)(qp + ks * 32 + q4 * 8);
  }
  float qs_s[2];
  #pragma unroll
  for (int mf = 0; mf < 2; ++mf)
    qs_s[mf] = scale * qs2[bh * 2048 + q0 + w * 32 + mf * 16 + r];

  f32x4 accO[2][4] = {};
  f32x4 lsum[2] = {};
  bf16x8 ones;
  #pragma unroll
  for (int j = 0; j < 8; ++j) ones[j] = (short)0x3F80;   // bf16 1.0

  const unsigned short* Kg = Kb + ((size_t)b * 2048) * 1024 + h * 64;
  const unsigned short* Vg = VT + ((size_t)bh * 64) * 2048;
  const float* kqb = ks2 + bh * 2048;

  // stage chunk 0 into buf 0
  #pragma unroll
  for (int g = 0; g < 2; ++g) {
    int slot = g * 256 + t;
    int khalf = slot >> 8, key = (slot >> 2) & 63, ko = (slot & 3) * 8;
    GLD_LDS(Kg + (size_t)key * 1024 + khalf * 32 + ko, &Ks[0][slot * 8]);
    int dd = slot >> 3, gg = (slot & 7) ^ (dd & 7);
    GLD_LDS(Vg + (size_t)dd * 2048 + gg * 8, &Vs[0][slot * 8]);
  }
  f32x4 kq[4];
  #pragma unroll
  for (int kfm = 0; kfm < 4; ++kfm) {
    f32x4 raw = *(const f32x4*)&kqb[kfm * 16 + q4 * 4];
    #pragma unroll
    for (int i = 0; i < 4; ++i) kq[kfm][i] = scale * raw[i];
  }

  #pragma unroll 2
  for (int c = 0; c < 32; ++c) {
    const int buf = c & 1;
    __syncthreads();                    // drains stage(c) (flew during compute(c-1))
    f32x4 kqn[4];
    if (c < 31) {
      #pragma unroll
      for (int g = 0; g < 2; ++g) {
        int slot = g * 256 + t;
        int khalf = slot >> 8, key = (slot >> 2) & 63, ko = (slot & 3) * 8;
        GLD_LDS(Kg + (size_t)((c + 1) * 64 + key) * 1024 + khalf * 32 + ko,
                &Ks[buf ^ 1][slot * 8]);
        int dd = slot >> 3, gg = (slot & 7) ^ (dd & 7);
        GLD_LDS(Vg + (size_t)dd * 2048 + (c + 1) * 64 + gg * 8,
                &Vs[buf ^ 1][slot * 8]);
      }
      #pragma unroll
      for (int kfm = 0; kfm < 4; ++kfm) {
        f32x4 raw = *(const f32x4*)&kqb[(c + 1) * 64 + kfm * 16 + q4 * 4];
        #pragma unroll
        for (int i = 0; i < 4; ++i) kqn[kfm][i] = scale * raw[i];
      }
    }

    // S^T = K.Q^T : A=K-frag (m=key), B=Q-frag (n=qrow)
    f32x4 accST[4][2] = {};
    #pragma unroll
    for (int ks = 0; ks < 2; ++ks) {
      #pragma unroll
      for (int kfm = 0; kfm < 4; ++kfm) {
        bf16x8 ka = *(const bf16x8*)&Ks[buf][(ks * 64 + kfm * 16 + r) * 32 + q4 * 8];
        accST[kfm][0] = __builtin_amdgcn_mfma_f32_16x16x32_bf16(ka, qf[0][ks], accST[kfm][0], 0, 0, 0);
        accST[kfm][1] = __builtin_amdgcn_mfma_f32_16x16x32_bf16(ka, qf[1][ks], accST[kfm][1], 0, 0, 0);
      }
    }

    // exp + pack: pf[cb][mf] holds P for keys tau(8q4+j), qrow = lane&15
    bf16x8 pf[2][2];
    #pragma unroll
    for (int cb = 0; cb < 2; ++cb) {
      #pragma unroll
      for (int mf = 0; mf < 2; ++mf) {
        unsigned int dw[4];
        #pragma unroll
        for (int half = 0; half < 2; ++half) {
          int kfm = cb * 2 + half;
          float pp[4];
          #pragma unroll
          for (int i = 0; i < 4; ++i) {
            float u = __builtin_fmaf(cc, accST[kfm][mf][i], -(kq[kfm][i] + qs_s[mf]));
            pp[i] = __builtin_amdgcn_exp2f(fminf(u, 0.f));
          }
          dw[half * 2 + 0] = (fbits(pp[0]) >> 16) | (fbits(pp[1]) & 0xFFFF0000u);
          dw[half * 2 + 1] = (fbits(pp[2]) >> 16) | (fbits(pp[3]) & 0xFFFF0000u);
        }
        union { unsigned int d[4]; bf16x8 v; } cv;
        cv.d[0] = dw[0]; cv.d[1] = dw[1]; cv.d[2] = dw[2]; cv.d[3] = dw[3];
        pf[cb][mf] = cv.v;
      }
    }

    // O += P.V ; lsum += P.ones   (B-frag: V[tau(k)][d], paired swizzled b64)
    #pragma unroll
    for (int cb = 0; cb < 2; ++cb) {
      #pragma unroll
      for (int mf = 0; mf < 2; ++mf)
        lsum[mf] = __builtin_amdgcn_mfma_f32_16x16x32_bf16(pf[cb][mf], ones, lsum[mf], 0, 0, 0);
      #pragma unroll
      for (int df = 0; df < 4; ++df) {
        int dloc = df * 16 + r;
        int e0 = (cb * 4 + (q4 >> 1)) ^ (r & 7);
        int e1 = (cb * 4 + 2 + (q4 >> 1)) ^ (r & 7);
        bf16x4 v0 = *(const bf16x4*)&Vs[buf][dloc * 64 + e0 * 8 + (q4 & 1) * 4];
        bf16x4 v1 = *(const bf16x4*)&Vs[buf][dloc * 64 + e1 * 8 + (q4 & 1) * 4];
        bf16x8 vb = __builtin_shufflevector(v0, v1, 0, 1, 2, 3, 4, 5, 6, 7);
        #pragma unroll
        for (int mf = 0; mf < 2; ++mf)
          accO[mf][df] = __builtin_amdgcn_mfma_f32_16x16x32_bf16(pf[cb][mf], vb, accO[mf][df], 0, 0, 0);
      }
    }
    if (c < 31) {
      #pragma unroll
      for (int kfm = 0; kfm < 4; ++kfm) kq[kfm] = kqn[kfm];
    }
  }
  #pragma unroll
  for (int mf = 0; mf < 2; ++mf) {
    float inv[4];
    #pragma unroll
    for (int i = 0; i < 4; ++i) inv[i] = 1.0f / lsum[mf][i];
    #pragma unroll
    for (int df = 0; df < 4; ++df) {
      int d = df * 16 + r;
      #pragma unroll
      for (int i = 0; i < 4; ++i) {
        int sq = q0 + w * 32 + mf * 16 + q4 * 4 + i;
        AO[(size_t)(b * 2048 + sq) * 1024 + h * 64 + d] = f2b(accO[mf][df][i] * inv[i]);
      }
    }
  }
}

// ------------------------------------------------------------- out GEMM
// 128x64 tile, BK=64, grid 16x32 = 512 blocks (2/CU).
__global__ __launch_bounds__(256, 2) void gemm_out_kernel(
    const unsigned short* __restrict__ A, const unsigned short* __restrict__ WT,
    const float* __restrict__ bo, float* __restrict__ Out) {
  __shared__ unsigned short As[2 * 128 * 32];   // [kh][row<128][32]
  __shared__ unsigned short Bs[2 * 64 * 32];    // [kh][row<64][32]
  const int t = threadIdx.x, w = t >> 6, lane = t & 63;
  const int r = lane & 15, q4 = lane >> 4;
  const int m0 = blockIdx.y * 128, n0 = blockIdx.x * 64;
  const int wr = (w >> 1) * 64, wc = (w & 1) * 32;
  const unsigned short* Ag = A + (size_t)m0 * 1024;
  const unsigned short* Wg = WT + (size_t)n0 * 1024;
  f32x4 acc[4][2] = {};
  for (int k0 = 0; k0 < 1024; k0 += 64) {
    #pragma unroll
    for (int g = 0; g < 4; ++g) {
      int slot = g * 256 + t;
      int kh = slot >> 9, row = (slot >> 2) & 127, ko = (slot & 3) * 8;
      GLD_LDS(Ag + (size_t)row * 1024 + k0 + kh * 32 + ko, &As[(g * 256 + w * 64) * 8]);
    }
    #pragma unroll
    for (int g = 0; g < 2; ++g) {
      int slot = g * 256 + t;
      int kh = slot >> 8, row = (slot >> 2) & 63, ko = (slot & 3) * 8;
      GLD_LDS(Wg + (size_t)row * 1024 + k0 + kh * 32 + ko, &Bs[(g * 256 + w * 64) * 8]);
    }
    __syncthreads();
    #pragma unroll
    for (int kh = 0; kh < 2; ++kh) {
      bf16x8 af[4], bfr[2];
      #pragma unroll
      for (int mf = 0; mf < 4; ++mf)
        af[mf] = *(const bf16x8*)&As[kh * 4096 + (wr + mf * 16 + r) * 32 + q4 * 8];
      #pragma unroll
      for (int nf = 0; nf < 2; ++nf)
        bfr[nf] = *(const bf16x8*)&Bs[kh * 2048 + (wc + nf * 16 + r) * 32 + q4 * 8];
      #pragma unroll
      for (int mf = 0; mf < 4; ++mf)
        #pragma unroll
        for (int nf = 0; nf < 2; ++nf)
          acc[mf][nf] = __builtin_amdgcn_mfma_f32_16x16x32_bf16(af[mf], bfr[nf], acc[mf][nf], 0, 0, 0);
    }
    __syncthreads();
  }
  #pragma unroll
  for (int nf = 0; nf < 2; ++nf) {
    int n = n0 + wc + nf * 16 + r;
    float bb = bo[n];
    #pragma unroll
    for (int mf = 0; mf < 4; ++mf) {
      int m = m0 + wr + mf * 16 + q4 * 4;
      f32x4 v = acc[mf][nf];
      #pragma unroll
      for (int i = 0; i < 4; ++i)
        Out[(size_t)(m + i) * 1024 + n] = v[i] + bb;
    }
  }
}

// ---------------------------------------------------------------- launch
extern "C" void kernel_launch(void* const* d_in, const int* in_sizes, int n_in,
                              void* d_out, int out_size, void* d_ws, size_t ws_size,
                              hipStream_t stream) {
  const float* X    = (const float*)d_in[0];
  const float* wq   = (const float*)d_in[1];
  const float* bq   = (const float*)d_in[2];
  const float* wk   = (const float*)d_in[3];
  const float* bk   = (const float*)d_in[4];
  const float* wv   = (const float*)d_in[5];
  const float* bv   = (const float*)d_in[6];
  const float* wo   = (const float*)d_in[7];
  const float* bo   = (const float*)d_in[8];
  const float* temp = (const float*)d_in[9];
  float* Out = (float*)d_out;

  char* ws = (char*)d_ws;
  unsigned short* Xb    = (unsigned short*)ws; ws += (size_t)4096 * 1024 * 2;
  unsigned short* WTqkv = (unsigned short*)ws; ws += (size_t)3072 * 1024 * 2;
  unsigned short* WTo   = (unsigned short*)ws; ws += (size_t)1024 * 1024 * 2;
  unsigned short* Qb    = (unsigned short*)ws; ws += (size_t)4096 * 1024 * 2;
  unsigned short* Kb    = (unsigned short*)ws; ws += (size_t)4096 * 1024 * 2;
  unsigned short* VT    = (unsigned short*)ws; ws += (size_t)4096 * 1024 * 2;
  unsigned short* AO    = (unsigned short*)ws; ws += (size_t)4096 * 1024 * 2;
  float* qs2 = (float*)ws; ws += (size_t)65536 * 4;
  float* ks2 = (float*)ws; ws += (size_t)65536 * 4;

  prep_kernel<<<dim3(16, 16, 5), 256, 0, stream>>>(X, wq, wk, wv, wo, Xb, WTqkv, WTo);
  gemm_qkv_kernel<<<dim3(24, 32), 256, 0, stream>>>(Xb, WTqkv, bq, bk, bv, Qb, Kb, VT, qs2, ks2);
  flash_kernel<<<dim3(16, 32), 256, 0, stream>>>(Qb, Kb, VT, qs2, ks2, temp, AO);
  gemm_out_kernel<<<dim3(16, 32), 256, 0, stream>>>(AO, WTo, bo, Out);
}

// Round 5
// 203.209 us; speedup vs baseline: 1.4277x; 1.0260x over previous
//
#include <hip/hip_runtime.h>
#include <stdint.h>
#include <stddef.h>

// EuclideanAttention MI355X, round 5.
// - VT global layout stores keys PERMUTED per 64-group (pos = H*32+q4*8+sub*4+i)
//   so flash's PV B-fragment is one ds_read_b128; qkv V-epilogue does an LDS
//   transpose that bakes the permutation in AND coalesces V writes (128B rows).
// - flash: V staged via XOR-unit swizzle (8 dwords/bank min, staging + reads).
// - qs2/ks2 pre-scaled by log2e/T in qkv epilogue.
// - AO aliased onto Xb (smaller ws).

#define LOG2E 1.44269504088896f

typedef __attribute__((ext_vector_type(8))) short bf16x8;
typedef __attribute__((ext_vector_type(4))) float f32x4;
typedef __attribute__((ext_vector_type(4))) unsigned short u16x4;
typedef __attribute__((ext_vector_type(8))) unsigned short u16x8;

__device__ __forceinline__ unsigned short f2b(float f) {
  union { float f; unsigned int u; } x; x.f = f;
  unsigned int u = x.u;
  u += 0x7fffu + ((u >> 16) & 1u);   // RNE
  return (unsigned short)(u >> 16);
}
__device__ __forceinline__ float b2f(unsigned short s) {
  union { unsigned int u; float f; } x; x.u = ((unsigned int)s) << 16;
  return x.f;
}
__device__ __forceinline__ unsigned int fbits(float f) {
  union { float f; unsigned int u; } x; x.f = f; return x.u;
}

// async global->LDS, 16B per lane. LDS dest = wave-uniform base + lane*16.
#define GLD_LDS(g, l) __builtin_amdgcn_global_load_lds( \
    (const __attribute__((address_space(1))) void*)(g), \
    (__attribute__((address_space(3))) void*)(l), 16, 0, 0)

// ------------------------------------------------- prep: W transpose + X cvt
__global__ void prep_kernel(const float* __restrict__ X,
                            const float* __restrict__ wq, const float* __restrict__ wk,
                            const float* __restrict__ wv, const float* __restrict__ wo,
                            unsigned short* __restrict__ Xb,
                            unsigned short* __restrict__ WTqkv, unsigned short* __restrict__ WTo) {
  int z = blockIdx.z;
  if (z == 4) {
    size_t base = ((size_t)(blockIdx.y * 16 + blockIdx.x)) * 16384;
    #pragma unroll
    for (int j = 0; j < 16; ++j) {
      size_t i = base + (size_t)(j * 256 + threadIdx.x) * 4;
      f32x4 v = *(const f32x4*)&X[i];
      u16x4 o;
      #pragma unroll
      for (int k = 0; k < 4; ++k) o[k] = f2b(v[k]);
      *(u16x4*)&Xb[i] = o;
    }
    return;
  }
  __shared__ float tile[64][65];
  const float* src = (z == 0) ? wq : (z == 1) ? wk : (z == 2) ? wv : wo;
  unsigned short* dst = (z < 3) ? (WTqkv + (size_t)z * 1024 * 1024) : WTo;
  int k0 = blockIdx.y * 64, n0 = blockIdx.x * 64;
  int rr = threadIdx.x >> 6, cc = threadIdx.x & 63;
  #pragma unroll
  for (int p = 0; p < 16; ++p) {
    int row = p * 4 + rr;
    tile[row][cc] = src[(size_t)(k0 + row) * 1024 + n0 + cc];
  }
  __syncthreads();
  #pragma unroll
  for (int p = 0; p < 16; ++p) {
    int row = p * 4 + rr;                       // n offset
    dst[(size_t)(n0 + row) * 1024 + k0 + cc] = f2b(tile[cc][row]);
  }
}

// -------------------------------------------------------------- QKV GEMM
// C[4096,3072] = X @ [wq|wk|wv] + bias. 128x128 tile, BK=64, 3 blocks/CU.
// Q/K epilogue emits pre-scaled ||row||^2 (x log2e/T). V epilogue transposes
// through LDS into VT[bh][d][s'] with keys permuted per 64-group:
//   pos = H*32 + q4*8 + sub*4 + i   for key k6 = H*32 + sub*16 + q4*4 + i.
__global__ __launch_bounds__(256, 3) void gemm_qkv_kernel(
    const unsigned short* __restrict__ X, const unsigned short* __restrict__ WT,
    const float* __restrict__ bq, const float* __restrict__ bk, const float* __restrict__ bv,
    const float* __restrict__ temp,
    unsigned short* __restrict__ Qb, unsigned short* __restrict__ Kb,
    unsigned short* __restrict__ VTo, float* __restrict__ qs2, float* __restrict__ ks2) {
  __shared__ __align__(16) unsigned short smem[16896];   // As(8192) Bs(8192) | Vt(2*64*132)
  unsigned short* As = smem;            // [kh<2][row<128][32]
  unsigned short* Bs = smem + 8192;
  const int t = threadIdx.x, w = t >> 6, lane = t & 63;
  const int r = lane & 15, q4 = lane >> 4;
  const int m0 = blockIdx.y * 128, n0 = blockIdx.x * 128;
  const int wr = (w >> 1) * 64, wc = (w & 1) * 64;
  const unsigned short* Xg = X + (size_t)m0 * 1024;
  const unsigned short* Wg = WT + (size_t)n0 * 1024;
  f32x4 acc[4][4] = {};
  for (int k0 = 0; k0 < 1024; k0 += 64) {
    #pragma unroll
    for (int g = 0; g < 4; ++g) {
      int slot = g * 256 + t;
      int kh = slot >> 9, row = (slot >> 2) & 127, ko = (slot & 3) * 8;
      GLD_LDS(Xg + (size_t)row * 1024 + k0 + kh * 32 + ko, &As[(g * 256 + w * 64) * 8]);
      GLD_LDS(Wg + (size_t)row * 1024 + k0 + kh * 32 + ko, &Bs[(g * 256 + w * 64) * 8]);
    }
    __syncthreads();
    #pragma unroll
    for (int kh = 0; kh < 2; ++kh) {
      bf16x8 af[4], bfr[4];
      #pragma unroll
      for (int mf = 0; mf < 4; ++mf)
        af[mf] = *(const bf16x8*)&As[kh * 4096 + (wr + mf * 16 + r) * 32 + q4 * 8];
      #pragma unroll
      for (int nf = 0; nf < 4; ++nf)
        bfr[nf] = *(const bf16x8*)&Bs[kh * 4096 + (wc + nf * 16 + r) * 32 + q4 * 8];
      #pragma unroll
      for (int mf = 0; mf < 4; ++mf)
        #pragma unroll
        for (int nf = 0; nf < 4; ++nf)
          acc[mf][nf] = __builtin_amdgcn_mfma_f32_16x16x32_bf16(af[mf], bfr[nf], acc[mf][nf], 0, 0, 0);
    }
    __syncthreads();
  }
  const int nblk = n0 >> 10;
  if (nblk < 2) {
    const float* bias = (nblk == 0) ? bq : bk;
    unsigned short* OutB = (nblk == 0) ? Qb : Kb;
    float* S2 = (nblk == 0) ? qs2 : ks2;
    const float sc = LOG2E / temp[0];
    const int nc0 = n0 & 1023;
    float s2a[4][4] = {};
    #pragma unroll
    for (int nf = 0; nf < 4; ++nf) {
      int n = nc0 + wc + nf * 16 + r;
      float bb = bias[n];
      #pragma unroll
      for (int mf = 0; mf < 4; ++mf) {
        int m = m0 + wr + mf * 16 + q4 * 4;
        f32x4 v = acc[mf][nf];
        #pragma unroll
        for (int i = 0; i < 4; ++i) {
          unsigned short os = f2b(v[i] + bb);
          OutB[(size_t)(m + i) * 1024 + n] = os;
          float xb = b2f(os);
          s2a[mf][i] += xb * xb;          // sum of squares of the ROUNDED value
        }
      }
    }
    #pragma unroll
    for (int mf = 0; mf < 4; ++mf)
      #pragma unroll
      for (int i = 0; i < 4; ++i) {
        float v = s2a[mf][i];
        v += __shfl_xor(v, 1, 64);
        v += __shfl_xor(v, 2, 64);
        v += __shfl_xor(v, 4, 64);
        v += __shfl_xor(v, 8, 64);
        s2a[mf][i] = v * sc;
      }
    if (r == 0) {
      int hh = (nc0 + wc) >> 6;
      #pragma unroll
      for (int mf = 0; mf < 4; ++mf) {
        int m = m0 + wr + mf * 16 + q4 * 4;
        int bb2 = m >> 11, ss = m & 2047;
        #pragma unroll
        for (int i = 0; i < 4; ++i)
          S2[(size_t)(bb2 * 16 + hh) * 2048 + ss + i] = s2a[mf][i];
      }
    }
  } else {
    // ---- V: LDS transpose -> permuted, coalesced VT writes
    unsigned short* Vt = smem;            // [head<2][d<64][G<2 * pos<64], stride 132
    const int c0 = n0 - 2048;
    const int head = w & 1;               // == wc>>6
    #pragma unroll
    for (int nf = 0; nf < 4; ++nf) {
      int c = c0 + wc + nf * 16 + r;
      float bb = bv[c];
      int d = c & 63;
      #pragma unroll
      for (int mf = 0; mf < 4; ++mf) {
        int mloc = wr + mf * 16 + q4 * 4;     // 0..124
        int G = mloc >> 6;
        int k6 = mloc & 63;
        int pos = (k6 >> 5) * 32 + ((k6 & 15) >> 2) * 8 + ((k6 >> 4) & 1) * 4;
        f32x4 v = acc[mf][nf];
        u16x4 pk;
        #pragma unroll
        for (int i = 0; i < 4; ++i) pk[i] = f2b(v[i] + bb);
        *(u16x4*)&Vt[(head * 64 + d) * 132 + G * 64 + pos] = pk;
      }
    }
    __syncthreads();
    int row = t >> 1, ch = t & 1;
    int hd = row >> 6, dd = row & 63;
    int hglob = (c0 >> 6) + hd;
    int bb2 = m0 >> 11, s0 = m0 & 2047;
    unsigned short* dst = &VTo[((size_t)((bb2 * 16 + hglob) * 64 + dd)) * 2048 + s0 + ch * 64];
    const unsigned short* srcL = &Vt[(hd * 64 + dd) * 132 + ch * 64];
    #pragma unroll
    for (int k2 = 0; k2 < 16; ++k2)
      *(u16x4*)&dst[k2 * 4] = *(const u16x4*)&srcL[k2 * 4];
  }
}

// ---------------------------------------------------------------- flash
// Block = (bh, 128 q-rows), 4 waves x 32 rows, 64-key double-buffered chunks.
// S^T = K.Q^T: C-frag doubles as PV A-operand (keys tau-permuted); VT global
// layout is pre-permuted, so a PV B-frag is ONE ds_read_b128 from the
// XOR-unit-swizzled V stage (8 dwords/bank everywhere).
__global__ __launch_bounds__(256, 2) void flash_kernel(
    const unsigned short* __restrict__ Qb, const unsigned short* __restrict__ Kb,
    const unsigned short* __restrict__ VT, const float* __restrict__ qs2,
    const float* __restrict__ ks2, const float* __restrict__ temp,
    unsigned short* __restrict__ AO) {
  __shared__ __align__(16) unsigned short Ks[2][64 * 64];   // [buf][half<2][key<64][dd<32]
  __shared__ __align__(16) unsigned short Vs[2][64 * 64];   // [buf] XOR-swizzled 16B units
  const int t = threadIdx.x, w = t >> 6, lane = t & 63;
  const int r = lane & 15, q4 = lane >> 4;
  const int bh = blockIdx.y, b = bh >> 4, h = bh & 15;
  const int q0 = blockIdx.x * 128;
  const float cc = 2.0f * LOG2E / temp[0];

  // Q fragments (B-operand: n=qrow=lane&15, k=q4*8+j)
  bf16x8 qf[2][2];
  #pragma unroll
  for (int mf = 0; mf < 2; ++mf) {
    int sq = q0 + w * 32 + mf * 16 + r;
    const unsigned short* qp = Qb + (size_t)(b * 2048 + sq) * 1024 + h * 64;
    #pragma unroll
    for (int ks = 0; ks < 2; ++ks) qf[mf][ks] = *(const bf16x8*)(qp + ks * 32 + q4 * 8);
  }
  float qs_s[2];
  #pragma unroll
  for (int mf = 0; mf < 2; ++mf)
    qs_s[mf] = qs2[bh * 2048 + q0 + w * 32 + mf * 16 + r];   // pre-scaled

  f32x4 accO[2][4] = {};
  f32x4 lsum[2] = {};
  bf16x8 ones;
  #pragma unroll
  for (int j = 0; j < 8; ++j) ones[j] = (short)0x3F80;   // bf16 1.0

  const unsigned short* Kg = Kb + ((size_t)b * 2048) * 1024 + h * 64;
  const unsigned short* Vg = VT + ((size_t)bh * 64) * 2048;
  const float* kqb = ks2 + bh * 2048;

  // stage chunk 0 into buf 0
  #pragma unroll
  for (int g = 0; g < 2; ++g) {
    int slot = g * 256 + t;
    int khalf = slot >> 8, key = (slot >> 2) & 63, ko = (slot & 3) * 8;
    GLD_LDS(Kg + (size_t)key * 1024 + khalf * 32 + ko, &Ks[0][slot * 8]);
    int dd = slot >> 3, pb = (slot & 7) ^ (dd & 7);
    GLD_LDS(Vg + (size_t)dd * 2048 + pb * 8, &Vs[0][slot * 8]);
  }
  f32x4 kq[4];
  #pragma unroll
  for (int kfm = 0; kfm < 4; ++kfm)
    kq[kfm] = *(const f32x4*)&kqb[kfm * 16 + q4 * 4];        // pre-scaled

  #pragma unroll 2
  for (int c = 0; c < 32; ++c) {
    const int buf = c & 1;
    __syncthreads();                    // drains stage(c) (flew during compute(c-1))
    f32x4 kqn[4];
    if (c < 31) {
      #pragma unroll
      for (int g = 0; g < 2; ++g) {
        int slot = g * 256 + t;
        int khalf = slot >> 8, key = (slot >> 2) & 63, ko = (slot & 3) * 8;
        GLD_LDS(Kg + (size_t)((c + 1) * 64 + key) * 1024 + khalf * 32 + ko,
                &Ks[buf ^ 1][slot * 8]);
        int dd = slot >> 3, pb = (slot & 7) ^ (dd & 7);
        GLD_LDS(Vg + (size_t)dd * 2048 + (c + 1) * 64 + pb * 8,
                &Vs[buf ^ 1][slot * 8]);
      }
      #pragma unroll
      for (int kfm = 0; kfm < 4; ++kfm)
        kqn[kfm] = *(const f32x4*)&kqb[(c + 1) * 64 + kfm * 16 + q4 * 4];
    }

    // S^T = K.Q^T : A=K-frag (m=key), B=Q-frag (n=qrow)
    f32x4 accST[4][2] = {};
    #pragma unroll
    for (int ks = 0; ks < 2; ++ks) {
      #pragma unroll
      for (int kfm = 0; kfm < 4; ++kfm) {
        bf16x8 ka = *(const bf16x8*)&Ks[buf][(ks * 64 + kfm * 16 + r) * 32 + q4 * 8];
        accST[kfm][0] = __builtin_amdgcn_mfma_f32_16x16x32_bf16(ka, qf[0][ks], accST[kfm][0], 0, 0, 0);
        accST[kfm][1] = __builtin_amdgcn_mfma_f32_16x16x32_bf16(ka, qf[1][ks], accST[kfm][1], 0, 0, 0);
      }
    }

    // exp + trunc-pack: pf[cb][mf] holds P for keys tau(8q4+j), qrow=lane&15
    bf16x8 pf[2][2];
    #pragma unroll
    for (int cb = 0; cb < 2; ++cb) {
      #pragma unroll
      for (int mf = 0; mf < 2; ++mf) {
        unsigned int dw[4];
        #pragma unroll
        for (int half = 0; half < 2; ++half) {
          int kfm = cb * 2 + half;
          float pp[4];
          #pragma unroll
          for (int i = 0; i < 4; ++i) {
            float u = __builtin_fmaf(cc, accST[kfm][mf][i], -(kq[kfm][i] + qs_s[mf]));
            pp[i] = __builtin_amdgcn_exp2f(fminf(u, 0.f));
          }
          dw[half * 2 + 0] = (fbits(pp[0]) >> 16) | (fbits(pp[1]) & 0xFFFF0000u);
          dw[half * 2 + 1] = (fbits(pp[2]) >> 16) | (fbits(pp[3]) & 0xFFFF0000u);
        }
        union { unsigned int d[4]; bf16x8 v; } cv;
        cv.d[0] = dw[0]; cv.d[1] = dw[1]; cv.d[2] = dw[2]; cv.d[3] = dw[3];
        pf[cb][mf] = cv.v;
      }
    }

    // O += P.V ; lsum += P.ones  (B-frag = one b128 from swizzled Vs)
    #pragma unroll
    for (int cb = 0; cb < 2; ++cb) {
      #pragma unroll
      for (int mf = 0; mf < 2; ++mf)
        lsum[mf] = __builtin_amdgcn_mfma_f32_16x16x32_bf16(pf[cb][mf], ones, lsum[mf], 0, 0, 0);
      #pragma unroll
      for (int df = 0; df < 4; ++df) {
        int dloc = df * 16 + r;
        int un = dloc * 8 + ((cb * 4 + q4) ^ (dloc & 7));
        bf16x8 vb = *(const bf16x8*)&Vs[buf][un * 8];
        #pragma unroll
        for (int mf = 0; mf < 2; ++mf)
          accO[mf][df] = __builtin_amdgcn_mfma_f32_16x16x32_bf16(pf[cb][mf], vb, accO[mf][df], 0, 0, 0);
      }
    }
    if (c < 31) {
      #pragma unroll
      for (int kfm = 0; kfm < 4; ++kfm) kq[kfm] = kqn[kfm];
    }
  }
  #pragma unroll
  for (int mf = 0; mf < 2; ++mf) {
    float inv[4];
    #pragma unroll
    for (int i = 0; i < 4; ++i) inv[i] = 1.0f / lsum[mf][i];
    #pragma unroll
    for (int df = 0; df < 4; ++df) {
      int d = df * 16 + r;
      #pragma unroll
      for (int i = 0; i < 4; ++i) {
        int sq = q0 + w * 32 + mf * 16 + q4 * 4 + i;
        AO[(size_t)(b * 2048 + sq) * 1024 + h * 64 + d] = f2b(accO[mf][df][i] * inv[i]);
      }
    }
  }
}

// ------------------------------------------------------------- out GEMM
// 128x64 tile, BK=64, grid 16x32 = 512 blocks (2/CU).
__global__ __launch_bounds__(256, 2) void gemm_out_kernel(
    const unsigned short* __restrict__ A, const unsigned short* __restrict__ WT,
    const float* __restrict__ bo, float* __restrict__ Out) {
  __shared__ __align__(16) unsigned short As[2 * 128 * 32];   // [kh][row<128][32]
  __shared__ __align__(16) unsigned short Bs[2 * 64 * 32];    // [kh][row<64][32]
  const int t = threadIdx.x, w = t >> 6, lane = t & 63;
  const int r = lane & 15, q4 = lane >> 4;
  const int m0 = blockIdx.y * 128, n0 = blockIdx.x * 64;
  const int wr = (w >> 1) * 64, wc = (w & 1) * 32;
  const unsigned short* Ag = A + (size_t)m0 * 1024;
  const unsigned short* Wg = WT + (size_t)n0 * 1024;
  f32x4 acc[4][2] = {};
  for (int k0 = 0; k0 < 1024; k0 += 64) {
    #pragma unroll
    for (int g = 0; g < 4; ++g) {
      int slot = g * 256 + t;
      int kh = slot >> 9, row = (slot >> 2) & 127, ko = (slot & 3) * 8;
      GLD_LDS(Ag + (size_t)row * 1024 + k0 + kh * 32 + ko, &As[(g * 256 + w * 64) * 8]);
    }
    #pragma unroll
    for (int g = 0; g < 2; ++g) {
      int slot = g * 256 + t;
      int kh = slot >> 8, row = (slot >> 2) & 63, ko = (slot & 3) * 8;
      GLD_LDS(Wg + (size_t)row * 1024 + k0 + kh * 32 + ko, &Bs[(g * 256 + w * 64) * 8]);
    }
    __syncthreads();
    #pragma unroll
    for (int kh = 0; kh < 2; ++kh) {
      bf16x8 af[4], bfr[2];
      #pragma unroll
      for (int mf = 0; mf < 4; ++mf)
        af[mf] = *(const bf16x8*)&As[kh * 4096 + (wr + mf * 16 + r) * 32 + q4 * 8];
      #pragma unroll
      for (int nf = 0; nf < 2; ++nf)
        bfr[nf] = *(const bf16x8*)&Bs[kh * 2048 + (wc + nf * 16 + r) * 32 + q4 * 8];
      #pragma unroll
      for (int mf = 0; mf < 4; ++mf)
        #pragma unroll
        for (int nf = 0; nf < 2; ++nf)
          acc[mf][nf] = __builtin_amdgcn_mfma_f32_16x16x32_bf16(af[mf], bfr[nf], acc[mf][nf], 0, 0, 0);
    }
    __syncthreads();
  }
  #pragma unroll
  for (int nf = 0; nf < 2; ++nf) {
    int n = n0 + wc + nf * 16 + r;
    float bb = bo[n];
    #pragma unroll
    for (int mf = 0; mf < 4; ++mf) {
      int m = m0 + wr + mf * 16 + q4 * 4;
      f32x4 v = acc[mf][nf];
      #pragma unroll
      for (int i = 0; i < 4; ++i)
        Out[(size_t)(m + i) * 1024 + n] = v[i] + bb;
    }
  }
}

// ---------------------------------------------------------------- launch
extern "C" void kernel_launch(void* const* d_in, const int* in_sizes, int n_in,
                              void* d_out, int out_size, void* d_ws, size_t ws_size,
                              hipStream_t stream) {
  const float* X    = (const float*)d_in[0];
  const float* wq   = (const float*)d_in[1];
  const float* bq   = (const float*)d_in[2];
  const float* wk   = (const float*)d_in[3];
  const float* bk   = (const float*)d_in[4];
  const float* wv   = (const float*)d_in[5];
  const float* bv   = (const float*)d_in[6];
  const float* wo   = (const float*)d_in[7];
  const float* bo   = (const float*)d_in[8];
  const float* temp = (const float*)d_in[9];
  float* Out = (float*)d_out;

  char* ws = (char*)d_ws;
  unsigned short* Xb    = (unsigned short*)ws; ws += (size_t)4096 * 1024 * 2;
  unsigned short* WTqkv = (unsigned short*)ws; ws += (size_t)3072 * 1024 * 2;
  unsigned short* WTo   = (unsigned short*)ws; ws += (size_t)1024 * 1024 * 2;
  unsigned short* Qb    = (unsigned short*)ws; ws += (size_t)4096 * 1024 * 2;
  unsigned short* Kb    = (unsigned short*)ws; ws += (size_t)4096 * 1024 * 2;
  unsigned short* VT    = (unsigned short*)ws; ws += (size_t)4096 * 1024 * 2;
  float* qs2 = (float*)ws; ws += (size_t)65536 * 4;
  float* ks2 = (float*)ws; ws += (size_t)65536 * 4;
  unsigned short* AO = Xb;   // Xb dead after gemm_qkv; reuse for flash output

  prep_kernel<<<dim3(16, 16, 5), 256, 0, stream>>>(X, wq, wk, wv, wo, Xb, WTqkv, WTo);
  gemm_qkv_kernel<<<dim3(24, 32), 256, 0, stream>>>(Xb, WTqkv, bq, bk, bv, temp, Qb, Kb, VT, qs2, ks2);
  flash_kernel<<<dim3(16, 32), 256, 0, stream>>>(Qb, Kb, VT, qs2, ks2, temp, AO);
  gemm_out_kernel<<<dim3(16, 32), 256, 0, stream>>>(AO, WTo, bo, Out);
}